// Round 1
// baseline (2997.208 us; speedup 1.0000x reference)
//
#include <hip/hip_runtime.h>

#define B_  2
#define S_  2048
#define NH_ 32
#define HD_ 128
#define H_  4096
#define H3_ 12288

typedef __bf16 bf16x8 __attribute__((ext_vector_type(8)));
typedef float  f32x4  __attribute__((ext_vector_type(4)));

__device__ __forceinline__ unsigned short f2bf(float f) {
  unsigned int u = __float_as_uint(f);
  u += 0x7fffu + ((u >> 16) & 1u);
  return (unsigned short)(u >> 16);
}
__device__ __forceinline__ void unpack8(uint4 r, float f[8]) {
  f[0] = __uint_as_float(r.x << 16); f[1] = __uint_as_float(r.x & 0xffff0000u);
  f[2] = __uint_as_float(r.y << 16); f[3] = __uint_as_float(r.y & 0xffff0000u);
  f[4] = __uint_as_float(r.z << 16); f[5] = __uint_as_float(r.z & 0xffff0000u);
  f[6] = __uint_as_float(r.w << 16); f[7] = __uint_as_float(r.w & 0xffff0000u);
}
__device__ __forceinline__ void gload_lds16(const void* g, void* l) {
  __builtin_amdgcn_global_load_lds(
      (const __attribute__((address_space(1))) unsigned int*)g,
      (__attribute__((address_space(3))) unsigned int*)l, 16, 0, 0);
}

// ---------------- f32 -> bf16 convert ----------------
__global__ __launch_bounds__(256) void cvt_bf16(const float* __restrict__ in,
                                                unsigned short* __restrict__ out,
                                                long n) {
  long i = ((long)blockIdx.x * 256 + threadIdx.x) * 4;
  const long stride = (long)gridDim.x * 256 * 4;
  for (; i < n; i += stride) {
    float4 v = *(const float4*)(in + i);
    ushort4 o;
    o.x = f2bf(v.x); o.y = f2bf(v.y); o.z = f2bf(v.z); o.w = f2bf(v.w);
    *(ushort4*)(out + i) = o;
  }
}

// ---------------- bf16 GEMM, C[m][n] = sum_k A[m][k]*Bt[n][k] (m97 structure) ----
// EPI 0: bf16 out + bias ; EPI 1: f32 out + bias + residual ; EPI 2: bf16 out
template <int EPI>
__global__ __launch_bounds__(256) void gemm_bt(
    const unsigned short* __restrict__ Abase, const unsigned short* __restrict__ Bbase,
    void* __restrict__ Cbase, const float* __restrict__ bias, const float* __restrict__ Res,
    int lda, int ldb, int ldc, int K,
    long sAb, long sAn, long sBb, long sBn, long sCb, long sCn)
{
  __shared__ __align__(16) unsigned short As[128][32];
  __shared__ __align__(16) unsigned short Bs[128][32];

  const int zz = blockIdx.z;
  const int zb = zz >> 5, zn = zz & 31;
  const unsigned short* A  = Abase + (long)zb * sAb + (long)zn * sAn;
  const unsigned short* Bm = Bbase + (long)zb * sBb + (long)zn * sBn;
  const long coff = (long)zb * sCb + (long)zn * sCn;

  const int m0 = blockIdx.y * 128;
  const int n0 = blockIdx.x * 128;
  const int tid = threadIdx.x;
  const int wave = tid >> 6;
  const int lane = tid & 63;
  const int wr = wave >> 1, wc = wave & 1;
  const int lr = lane & 15, kq = lane >> 4;
  const int srow = wave * 16 + (lane >> 2);   // row this lane stages
  const int scol = (lane & 3) * 8;            // k-offset (elements) this lane stages

  const f32x4 zero = {0.0f, 0.0f, 0.0f, 0.0f};
  f32x4 acc[4][4];
#pragma unroll
  for (int m = 0; m < 4; ++m)
#pragma unroll
    for (int n = 0; n < 4; ++n) acc[m][n] = zero;

  for (int k0 = 0; k0 < K; k0 += 32) {
    const unsigned short* ga = A  + (long)(m0 + srow) * lda + k0 + scol;
    const unsigned short* gb = Bm + (long)(n0 + srow) * ldb + k0 + scol;
    // LDS dest is wave-uniform base; HW adds lane*16B (linear rows of 64B)
    gload_lds16(ga,                   &As[wave * 16][0]);
    gload_lds16(ga + (long)64 * lda,  &As[64 + wave * 16][0]);
    gload_lds16(gb,                   &Bs[wave * 16][0]);
    gload_lds16(gb + (long)64 * ldb,  &Bs[64 + wave * 16][0]);
    __syncthreads();

    bf16x8 av[4], bv[4];
#pragma unroll
    for (int m = 0; m < 4; ++m) av[m] = *(const bf16x8*)&As[wr * 64 + m * 16 + lr][kq * 8];
#pragma unroll
    for (int n = 0; n < 4; ++n) bv[n] = *(const bf16x8*)&Bs[wc * 64 + n * 16 + lr][kq * 8];
#pragma unroll
    for (int m = 0; m < 4; ++m)
#pragma unroll
      for (int n = 0; n < 4; ++n)
        acc[m][n] = __builtin_amdgcn_mfma_f32_16x16x32_bf16(av[m], bv[n], acc[m][n], 0, 0, 0);
    __syncthreads();
  }

  // epilogue: C/D layout col=lane&15, row=(lane>>4)*4+r
#pragma unroll
  for (int m = 0; m < 4; ++m) {
    const int grow0 = m0 + wr * 64 + m * 16 + kq * 4;
#pragma unroll
    for (int n = 0; n < 4; ++n) {
      const int gcol = n0 + wc * 64 + n * 16 + lr;
#pragma unroll
      for (int r = 0; r < 4; ++r) {
        const long gi = coff + (long)(grow0 + r) * ldc + gcol;
        float v = acc[m][n][r];
        if (EPI == 0) {
          ((unsigned short*)Cbase)[gi] = f2bf(v + bias[gcol]);
        } else if (EPI == 1) {
          ((float*)Cbase)[gi] = v + bias[gcol] + Res[gi];
        } else {
          ((unsigned short*)Cbase)[gi] = f2bf(v);
        }
      }
    }
  }
}

// ---------------- G = Q^T Q per (b,n), chunked over s, atomic reduce ----------
__global__ __launch_bounds__(256) void compute_g(const unsigned short* __restrict__ fused,
                                                 float* __restrict__ G)
{
  __shared__ float Qs[64][128];
  const int z = blockIdx.x;            // b*32+n
  const int b = z >> 5, n = z & 31;
  const unsigned short* Q = fused + (long)b * S_ * H3_ + n * 384;
  const int t = threadIdx.x;
  const int t1 = t >> 4, t2 = t & 15;  // thread owns G[t1*8.., t2*8..] 8x8
  float acc[8][8];
#pragma unroll
  for (int a = 0; a < 8; ++a)
#pragma unroll
    for (int c = 0; c < 8; ++c) acc[a][c] = 0.f;

  const int sbeg = blockIdx.y * 512;
  for (int s0 = sbeg; s0 < sbeg + 512; s0 += 64) {
#pragma unroll
    for (int ii = 0; ii < 4; ++ii) {
      const int r = ii * 16 + t1;
      float f[8];
      unpack8(*(const uint4*)(Q + (long)(s0 + r) * H3_ + t2 * 8), f);
#pragma unroll
      for (int j = 0; j < 8; ++j) Qs[r][t2 * 8 + j] = f[j];
    }
    __syncthreads();
    for (int ss = 0; ss < 64; ++ss) {
      float qa[8], qb[8];
#pragma unroll
      for (int j = 0; j < 8; ++j) { qa[j] = Qs[ss][t1 * 8 + j]; qb[j] = Qs[ss][t2 * 8 + j]; }
#pragma unroll
      for (int a = 0; a < 8; ++a)
#pragma unroll
        for (int c = 0; c < 8; ++c) acc[a][c] += qa[a] * qb[c];
    }
    __syncthreads();
  }
  float* Gz = G + (long)z * 16384;
#pragma unroll
  for (int a = 0; a < 8; ++a)
#pragma unroll
    for (int c = 0; c < 8; ++c)
      atomicAdd(&Gz[(t1 * 8 + a) * 128 + t2 * 8 + c], acc[a][c]);
}

// ---------------- in-place Gauss-Jordan inverse of SPD 128x128 ----------------
__global__ __launch_bounds__(256) void invert_g(const float* __restrict__ G,
                                                unsigned short* __restrict__ Ginv)
{
  __shared__ float M[128][128];
  const int z = blockIdx.x;
  const int t = threadIdx.x;
  for (int idx = t; idx < 16384; idx += 256) M[idx >> 7][idx & 127] = G[(long)z * 16384 + idx];
  __syncthreads();
  const int r = t >> 1, ch = t & 1;
  for (int p = 0; p < 128; ++p) {
    const float invp = 1.0f / M[p][p];
    __syncthreads();
    if (t < 128) M[p][t] = (t == p) ? invp : M[p][t] * invp;
    __syncthreads();
    const float f = (r == p) ? 0.f : M[r][p];
    __syncthreads();
    if (r != p) {
#pragma unroll 4
      for (int jj = 0; jj < 64; ++jj) {
        const int j = ch * 64 + jj;
        const float cur = (j == p) ? 0.f : M[r][j];
        M[r][j] = cur - f * M[p][j];
      }
    }
    __syncthreads();
  }
  for (int idx = t; idx < 16384; idx += 256)
    Ginv[(long)z * 16384 + idx] = f2bf(M[idx >> 7][idx & 127]);
}

// ---------------- per-position 32x32 head attention ----------------
__global__ __launch_bounds__(256) void attn_pos(
    const unsigned short* __restrict__ fused, const unsigned short* __restrict__ Zb,
    const float* __restrict__ alibi, unsigned short* __restrict__ ctx)
{
  __shared__ __align__(16) unsigned short qkv[H3_];   // 24KB: q,k,v interleaved per head
  __shared__ __align__(16) unsigned short zsh[H_];    // 8KB: z = Ginv*q per head
  __shared__ float wsh[NH_][NH_ + 1];
  __shared__ float pden[NH_];
  __shared__ float alib[NH_];

  const int s = blockIdx.x, b = blockIdx.y;
  const int t = threadIdx.x;
  const unsigned short* src = fused + ((long)b * S_ + s) * H3_;
  for (int i = t * 8; i < H3_; i += 2048) *(uint4*)&qkv[i] = *(const uint4*)&src[i];
  const unsigned short* zsrc = Zb + ((long)b * S_ + s) * H_;
  for (int i = t * 8; i < H_; i += 2048) *(uint4*)&zsh[i] = *(const uint4*)&zsrc[i];
  if (t < NH_) alib[t] = 0.08838834764831845f * alibi[((long)(b * NH_ + t)) * S_ + s];
  __syncthreads();

  // w[i][j] = (1/128) q_i.k_j + scale*alibi_j * q_i.z_j ; thread: i=t>>3, j in j0..j0+3
  const int i = t >> 3;
  const int j0 = (t & 7) * 4;
  const int rot = (i ^ (t & 7)) & 15;   // stagger d-blocks to spread LDS banks
  float aqk[4] = {0.f, 0.f, 0.f, 0.f};
  float aqz[4] = {0.f, 0.f, 0.f, 0.f};
  for (int dbi = 0; dbi < 16; ++dbi) {
    const int d0b = ((dbi + rot) & 15) * 8;
    float qf[8];
    unpack8(*(const uint4*)&qkv[i * 384 + d0b], qf);
#pragma unroll
    for (int jj = 0; jj < 4; ++jj) {
      const int j = j0 + jj;
      float kf[8], zf[8];
      unpack8(*(const uint4*)&qkv[j * 384 + 128 + d0b], kf);
      unpack8(*(const uint4*)&zsh[j * 128 + d0b], zf);
#pragma unroll
      for (int d = 0; d < 8; ++d) { aqk[jj] += qf[d] * kf[d]; aqz[jj] += qf[d] * zf[d]; }
    }
  }
#pragma unroll
  for (int jj = 0; jj < 4; ++jj)
    wsh[i][j0 + jj] = 0.0078125f * aqk[jj] + alib[j0 + jj] * aqz[jj];
  __syncthreads();

  if (t < NH_) {
    float m = -1e30f;
    for (int j = 0; j < NH_; ++j) m = fmaxf(m, wsh[t][j]);
    float ssum = 0.f;
    for (int j = 0; j < NH_; ++j) { float e = __expf(wsh[t][j] - m); wsh[t][j] = e; ssum += e; }
    pden[t] = 1.0f / (ssum + 1e-8f);
  }
  __syncthreads();

  // ctx_i[d] = sum_j p_ij v_j[d] ; thread: i=t>>3, 16 d's at d0
  const int d0 = (t & 7) * 16;
  float acc[16];
#pragma unroll
  for (int d = 0; d < 16; ++d) acc[d] = 0.f;
  for (int j = 0; j < NH_; ++j) {
    const float p = wsh[i][j];
    float vf[16];
    unpack8(*(const uint4*)&qkv[j * 384 + 256 + d0], vf);
    unpack8(*(const uint4*)&qkv[j * 384 + 256 + d0 + 8], vf + 8);
#pragma unroll
    for (int d = 0; d < 16; ++d) acc[d] += p * vf[d];
  }
  const float inv = pden[i];
  union { uint4 u[2]; unsigned short us[16]; } ov;
#pragma unroll
  for (int d = 0; d < 16; ++d) ov.us[d] = f2bf(acc[d] * inv);
  unsigned short* cp = ctx + ((long)b * S_ + s) * H_ + i * HD_ + d0;
  *(uint4*)&cp[0] = ov.u[0];
  *(uint4*)&cp[8] = ov.u[1];
}

// -----------------------------------------------------------------------------
extern "C" void kernel_launch(void* const* d_in, const int* in_sizes, int n_in,
                              void* d_out, int out_size, void* d_ws, size_t ws_size,
                              hipStream_t stream)
{
  (void)in_sizes; (void)n_in; (void)out_size; (void)ws_size;
  const float* hidden   = (const float*)d_in[0];
  const float* residual = (const float*)d_in[1];
  const float* alibi    = (const float*)d_in[2];
  // d_in[3] attention_mask: unused by the reference
  const float* Wqkv     = (const float*)d_in[4];
  const float* bqkv     = (const float*)d_in[5];
  const float* Wd       = (const float*)d_in[6];
  const float* bd       = (const float*)d_in[7];
  float* out = (float*)d_out;

  char* ws = (char*)d_ws;
  size_t off = 0;
  auto carve = [&](size_t bytes) -> void* {
    void* p = ws + off;
    off += (bytes + 255) & ~(size_t)255;
    return p;
  };
  const long nHid = (long)B_ * S_ * H_;   // 16,777,216
  const long nWq  = (long)H3_ * H_;       // 50,331,648
  unsigned short* hid_bf   = (unsigned short*)carve((size_t)nHid * 2);
  unsigned short* wqkv_bf  = (unsigned short*)carve((size_t)nWq * 2);
  unsigned short* wd_bf    = (unsigned short*)carve((size_t)H_ * H_ * 2);
  unsigned short* fused_bf = (unsigned short*)carve((size_t)B_ * S_ * H3_ * 2);
  unsigned short* z_bf     = (unsigned short*)carve((size_t)nHid * 2);
  unsigned short* ctx_bf   = (unsigned short*)carve((size_t)nHid * 2);
  float*          Gbuf     = (float*)carve((size_t)64 * 16384 * 4);
  unsigned short* ginv_bf  = (unsigned short*)carve((size_t)64 * 16384 * 2);

  // 1) bf16 casts
  cvt_bf16<<<2048, 256, 0, stream>>>(hidden, hid_bf, nHid);
  cvt_bf16<<<2048, 256, 0, stream>>>(Wqkv, wqkv_bf, nWq);
  cvt_bf16<<<2048, 256, 0, stream>>>(Wd, wd_bf, (long)H_ * H_);

  // 2) fused = hidden @ Wqkv^T + b_qkv  (bf16 out)
  gemm_bt<0><<<dim3(H3_ / 128, (B_ * S_) / 128, 1), 256, 0, stream>>>(
      hid_bf, wqkv_bf, fused_bf, bqkv, nullptr, H_, H_, H3_, H_, 0, 0, 0, 0, 0, 0);

  // 3) G = Q^T Q per (b,n); then Ginv via Gauss-Jordan (SPD)
  hipMemsetAsync(Gbuf, 0, (size_t)64 * 16384 * 4, stream);
  compute_g<<<dim3(64, 4), 256, 0, stream>>>(fused_bf, Gbuf);
  invert_g<<<64, 256, 0, stream>>>(Gbuf, ginv_bf);

  // 4) Z[b,s,n,:] = Ginv_{b,n} q_{b,n}(s)   (batched GEMM, Ginv symmetric)
  gemm_bt<2><<<dim3(1, S_ / 128, 64), 256, 0, stream>>>(
      fused_bf, ginv_bf, z_bf, nullptr, nullptr, H3_, HD_, H_, HD_,
      (long)S_ * H3_, 384, (long)32 * 16384, 16384, (long)S_ * H_, HD_);

  // 5) per-position 32x32 head attention -> ctx (bf16)
  attn_pos<<<dim3(S_, B_), 256, 0, stream>>>(fused_bf, z_bf, alibi, ctx_bf);

  // 6) out = ctx @ Wd^T + b_dense + residual  (f32 out)
  gemm_bt<1><<<dim3(H_ / 128, (B_ * S_) / 128, 1), 256, 0, stream>>>(
      ctx_bf, wd_bf, out, bd, residual, H_, H_, H_, H_, 0, 0, 0, 0, 0, 0);
}

// Round 2
// 1690.581 us; speedup vs baseline: 1.7729x; 1.7729x over previous
//
#include <hip/hip_runtime.h>

#define B_  2
#define S_  2048
#define NH_ 32
#define HD_ 128
#define H_  4096
#define H3_ 12288

typedef __bf16 bf16x8 __attribute__((ext_vector_type(8)));
typedef float  f32x4  __attribute__((ext_vector_type(4)));

__device__ __forceinline__ unsigned short f2bf(float f) {
  unsigned int u = __float_as_uint(f);
  u += 0x7fffu + ((u >> 16) & 1u);
  return (unsigned short)(u >> 16);
}
__device__ __forceinline__ void unpack8(uint4 r, float f[8]) {
  f[0] = __uint_as_float(r.x << 16); f[1] = __uint_as_float(r.x & 0xffff0000u);
  f[2] = __uint_as_float(r.y << 16); f[3] = __uint_as_float(r.y & 0xffff0000u);
  f[4] = __uint_as_float(r.z << 16); f[5] = __uint_as_float(r.z & 0xffff0000u);
  f[6] = __uint_as_float(r.w << 16); f[7] = __uint_as_float(r.w & 0xffff0000u);
}
__device__ __forceinline__ void gload_lds16(const void* g, void* l) {
  __builtin_amdgcn_global_load_lds(
      (const __attribute__((address_space(1))) unsigned int*)g,
      (__attribute__((address_space(3))) unsigned int*)l, 16, 0, 0);
}

// ---------------- f32 -> bf16 convert ----------------
__global__ __launch_bounds__(256) void cvt_bf16(const float* __restrict__ in,
                                                unsigned short* __restrict__ out,
                                                long n) {
  long i = ((long)blockIdx.x * 256 + threadIdx.x) * 4;
  const long stride = (long)gridDim.x * 256 * 4;
  for (; i < n; i += stride) {
    float4 v = *(const float4*)(in + i);
    ushort4 o;
    o.x = f2bf(v.x); o.y = f2bf(v.y); o.z = f2bf(v.z); o.w = f2bf(v.w);
    *(ushort4*)(out + i) = o;
  }
}

// ---------------- bf16 GEMM, C[m][n] = sum_k A[m][k]*Bt[n][k] (m97 structure) ----
// EPI 0: bf16 out + bias ; EPI 1: f32 out + bias + residual ; EPI 2: bf16 out
template <int EPI>
__global__ __launch_bounds__(256) void gemm_bt(
    const unsigned short* __restrict__ Abase, const unsigned short* __restrict__ Bbase,
    void* __restrict__ Cbase, const float* __restrict__ bias, const float* __restrict__ Res,
    int lda, int ldb, int ldc, int K,
    long sAb, long sAn, long sBb, long sBn, long sCb, long sCn)
{
  __shared__ __align__(16) unsigned short As[128][32];
  __shared__ __align__(16) unsigned short Bs[128][32];

  const int zz = blockIdx.z;
  const int zb = zz >> 5, zn = zz & 31;
  const unsigned short* A  = Abase + (long)zb * sAb + (long)zn * sAn;
  const unsigned short* Bm = Bbase + (long)zb * sBb + (long)zn * sBn;
  const long coff = (long)zb * sCb + (long)zn * sCn;

  const int m0 = blockIdx.y * 128;
  const int n0 = blockIdx.x * 128;
  const int tid = threadIdx.x;
  const int wave = tid >> 6;
  const int lane = tid & 63;
  const int wr = wave >> 1, wc = wave & 1;
  const int lr = lane & 15, kq = lane >> 4;
  const int srow = wave * 16 + (lane >> 2);   // row this lane stages
  const int scol = (lane & 3) * 8;            // k-offset (elements) this lane stages

  const f32x4 zero = {0.0f, 0.0f, 0.0f, 0.0f};
  f32x4 acc[4][4];
#pragma unroll
  for (int m = 0; m < 4; ++m)
#pragma unroll
    for (int n = 0; n < 4; ++n) acc[m][n] = zero;

  for (int k0 = 0; k0 < K; k0 += 32) {
    const unsigned short* ga = A  + (long)(m0 + srow) * lda + k0 + scol;
    const unsigned short* gb = Bm + (long)(n0 + srow) * ldb + k0 + scol;
    // LDS dest is wave-uniform base; HW adds lane*16B (linear rows of 64B)
    gload_lds16(ga,                   &As[wave * 16][0]);
    gload_lds16(ga + (long)64 * lda,  &As[64 + wave * 16][0]);
    gload_lds16(gb,                   &Bs[wave * 16][0]);
    gload_lds16(gb + (long)64 * ldb,  &Bs[64 + wave * 16][0]);
    __syncthreads();

    bf16x8 av[4], bv[4];
#pragma unroll
    for (int m = 0; m < 4; ++m) av[m] = *(const bf16x8*)&As[wr * 64 + m * 16 + lr][kq * 8];
#pragma unroll
    for (int n = 0; n < 4; ++n) bv[n] = *(const bf16x8*)&Bs[wc * 64 + n * 16 + lr][kq * 8];
#pragma unroll
    for (int m = 0; m < 4; ++m)
#pragma unroll
      for (int n = 0; n < 4; ++n)
        acc[m][n] = __builtin_amdgcn_mfma_f32_16x16x32_bf16(av[m], bv[n], acc[m][n], 0, 0, 0);
    __syncthreads();
  }

  // epilogue: C/D layout col=lane&15, row=(lane>>4)*4+r
#pragma unroll
  for (int m = 0; m < 4; ++m) {
    const int grow0 = m0 + wr * 64 + m * 16 + kq * 4;
#pragma unroll
    for (int n = 0; n < 4; ++n) {
      const int gcol = n0 + wc * 64 + n * 16 + lr;
#pragma unroll
      for (int r = 0; r < 4; ++r) {
        const long gi = coff + (long)(grow0 + r) * ldc + gcol;
        float v = acc[m][n][r];
        if (EPI == 0) {
          ((unsigned short*)Cbase)[gi] = f2bf(v + bias[gcol]);
        } else if (EPI == 1) {
          ((float*)Cbase)[gi] = v + bias[gcol] + Res[gi];
        } else {
          ((unsigned short*)Cbase)[gi] = f2bf(v);
        }
      }
    }
  }
}

// ---------------- G = Q^T Q per (b,n), chunked over s, atomic reduce ----------
__global__ __launch_bounds__(256) void compute_g(const unsigned short* __restrict__ fused,
                                                 float* __restrict__ G)
{
  __shared__ float Qs[64][128];
  const int z = blockIdx.x;            // b*32+n
  const int b = z >> 5, n = z & 31;
  const unsigned short* Q = fused + (long)b * S_ * H3_ + n * 384;
  const int t = threadIdx.x;
  const int t1 = t >> 4, t2 = t & 15;  // thread owns G[t1*8.., t2*8..] 8x8
  float acc[8][8];
#pragma unroll
  for (int a = 0; a < 8; ++a)
#pragma unroll
    for (int c = 0; c < 8; ++c) acc[a][c] = 0.f;

  const int sbeg = blockIdx.y * 512;
  for (int s0 = sbeg; s0 < sbeg + 512; s0 += 64) {
#pragma unroll
    for (int ii = 0; ii < 4; ++ii) {
      const int r = ii * 16 + t1;
      float f[8];
      unpack8(*(const uint4*)(Q + (long)(s0 + r) * H3_ + t2 * 8), f);
#pragma unroll
      for (int j = 0; j < 8; ++j) Qs[r][t2 * 8 + j] = f[j];
    }
    __syncthreads();
    for (int ss = 0; ss < 64; ++ss) {
      float qa[8], qb[8];
#pragma unroll
      for (int j = 0; j < 8; ++j) { qa[j] = Qs[ss][t1 * 8 + j]; qb[j] = Qs[ss][t2 * 8 + j]; }
#pragma unroll
      for (int a = 0; a < 8; ++a)
#pragma unroll
        for (int c = 0; c < 8; ++c) acc[a][c] += qa[a] * qb[c];
    }
    __syncthreads();
  }
  float* Gz = G + (long)z * 16384;
#pragma unroll
  for (int a = 0; a < 8; ++a)
#pragma unroll
    for (int c = 0; c < 8; ++c)
      atomicAdd(&Gz[(t1 * 8 + a) * 128 + t2 * 8 + c], acc[a][c]);
}

// ---------------- in-place Gauss-Jordan inverse of SPD 128x128 ----------------
// Conflict-free layout: thread t owns column c = t&127, rows rh*64..rh*64+63
// (rh = t>>7). M[r][c] accesses are lane-consecutive (2 lanes/bank = free);
// pivot-column reads M[r][p] are wave-uniform broadcasts, preloaded into
// registers between two barriers so the c==p writer can't race other waves.
__global__ __launch_bounds__(256) void invert_g(const float* __restrict__ G,
                                                unsigned short* __restrict__ Ginv)
{
  __shared__ float M[128][128];
  const int z = blockIdx.x;
  const int t = threadIdx.x;
  for (int idx = t; idx < 16384; idx += 256)
    M[idx >> 7][idx & 127] = G[(long)z * 16384 + idx];

  const int c  = t & 127;
  const int rh = t >> 7;          // row half: rows rh*64 .. rh*64+63
  const int rbase = rh * 64;

  for (int p = 0; p < 128; ++p) {
    __syncthreads();                       // M consistent from previous pivot
    const float invp = 1.0f / M[p][p];     // broadcast read
    float mpc = M[p][c];                   // lane-consecutive read
    mpc = (c == p) ? invp : mpc * invp;    // scaled pivot-row value (register)
    float fr[64];
#pragma unroll
    for (int i = 0; i < 64; ++i) fr[i] = M[rbase + i][p];  // broadcast reads
    __syncthreads();                       // all reads done before any write
#pragma unroll
    for (int i = 0; i < 64; ++i) {
      const int r = rbase + i;
      if (r == p) {
        M[r][c] = mpc;                               // scaled pivot row
      } else {
        const float cur = (c == p) ? 0.f : M[r][c];
        M[r][c] = cur - fr[i] * mpc;                 // rank-1 update
      }
    }
  }
  __syncthreads();
  for (int idx = t; idx < 16384; idx += 256)
    Ginv[(long)z * 16384 + idx] = f2bf(M[idx >> 7][idx & 127]);
}

// ---------------- per-position 32x32 head attention ----------------
__global__ __launch_bounds__(256) void attn_pos(
    const unsigned short* __restrict__ fused, const unsigned short* __restrict__ Zb,
    const float* __restrict__ alibi, unsigned short* __restrict__ ctx)
{
  __shared__ __align__(16) unsigned short qkv[H3_];   // 24KB: q,k,v interleaved per head
  __shared__ __align__(16) unsigned short zsh[H_];    // 8KB: z = Ginv*q per head
  __shared__ float wsh[NH_][NH_ + 1];
  __shared__ float pden[NH_];
  __shared__ float alib[NH_];

  const int s = blockIdx.x, b = blockIdx.y;
  const int t = threadIdx.x;
  const unsigned short* src = fused + ((long)b * S_ + s) * H3_;
  for (int i = t * 8; i < H3_; i += 2048) *(uint4*)&qkv[i] = *(const uint4*)&src[i];
  const unsigned short* zsrc = Zb + ((long)b * S_ + s) * H_;
  for (int i = t * 8; i < H_; i += 2048) *(uint4*)&zsh[i] = *(const uint4*)&zsrc[i];
  if (t < NH_) alib[t] = 0.08838834764831845f * alibi[((long)(b * NH_ + t)) * S_ + s];
  __syncthreads();

  // w[i][j] = (1/128) q_i.k_j + scale*alibi_j * q_i.z_j ; thread: i=t>>3, j in j0..j0+3
  const int i = t >> 3;
  const int j0 = (t & 7) * 4;
  const int rot = (i ^ (t & 7)) & 15;   // stagger d-blocks to spread LDS banks
  float aqk[4] = {0.f, 0.f, 0.f, 0.f};
  float aqz[4] = {0.f, 0.f, 0.f, 0.f};
  for (int dbi = 0; dbi < 16; ++dbi) {
    const int d0b = ((dbi + rot) & 15) * 8;
    float qf[8];
    unpack8(*(const uint4*)&qkv[i * 384 + d0b], qf);
#pragma unroll
    for (int jj = 0; jj < 4; ++jj) {
      const int j = j0 + jj;
      float kf[8], zf[8];
      unpack8(*(const uint4*)&qkv[j * 384 + 128 + d0b], kf);
      unpack8(*(const uint4*)&zsh[j * 128 + d0b], zf);
#pragma unroll
      for (int d = 0; d < 8; ++d) { aqk[jj] += qf[d] * kf[d]; aqz[jj] += qf[d] * zf[d]; }
    }
  }
#pragma unroll
  for (int jj = 0; jj < 4; ++jj)
    wsh[i][j0 + jj] = 0.0078125f * aqk[jj] + alib[j0 + jj] * aqz[jj];
  __syncthreads();

  if (t < NH_) {
    float m = -1e30f;
    for (int j = 0; j < NH_; ++j) m = fmaxf(m, wsh[t][j]);
    float ssum = 0.f;
    for (int j = 0; j < NH_; ++j) { float e = __expf(wsh[t][j] - m); wsh[t][j] = e; ssum += e; }
    pden[t] = 1.0f / (ssum + 1e-8f);
  }
  __syncthreads();

  // ctx_i[d] = sum_j p_ij v_j[d] ; thread: i=t>>3, 16 d's at d0
  const int d0 = (t & 7) * 16;
  float acc[16];
#pragma unroll
  for (int d = 0; d < 16; ++d) acc[d] = 0.f;
  for (int j = 0; j < NH_; ++j) {
    const float p = wsh[i][j];
    float vf[16];
    unpack8(*(const uint4*)&qkv[j * 384 + 256 + d0], vf);
    unpack8(*(const uint4*)&qkv[j * 384 + 256 + d0 + 8], vf + 8);
#pragma unroll
    for (int d = 0; d < 16; ++d) acc[d] += p * vf[d];
  }
  const float inv = pden[i];
  union { uint4 u[2]; unsigned short us[16]; } ov;
#pragma unroll
  for (int d = 0; d < 16; ++d) ov.us[d] = f2bf(acc[d] * inv);
  unsigned short* cp = ctx + ((long)b * S_ + s) * H_ + i * HD_ + d0;
  *(uint4*)&cp[0] = ov.u[0];
  *(uint4*)&cp[8] = ov.u[1];
}

// -----------------------------------------------------------------------------
extern "C" void kernel_launch(void* const* d_in, const int* in_sizes, int n_in,
                              void* d_out, int out_size, void* d_ws, size_t ws_size,
                              hipStream_t stream)
{
  (void)in_sizes; (void)n_in; (void)out_size; (void)ws_size;
  const float* hidden   = (const float*)d_in[0];
  const float* residual = (const float*)d_in[1];
  const float* alibi    = (const float*)d_in[2];
  // d_in[3] attention_mask: unused by the reference
  const float* Wqkv     = (const float*)d_in[4];
  const float* bqkv     = (const float*)d_in[5];
  const float* Wd       = (const float*)d_in[6];
  const float* bd       = (const float*)d_in[7];
  float* out = (float*)d_out;

  char* ws = (char*)d_ws;
  size_t off = 0;
  auto carve = [&](size_t bytes) -> void* {
    void* p = ws + off;
    off += (bytes + 255) & ~(size_t)255;
    return p;
  };
  const long nHid = (long)B_ * S_ * H_;   // 16,777,216
  const long nWq  = (long)H3_ * H_;       // 50,331,648
  unsigned short* hid_bf   = (unsigned short*)carve((size_t)nHid * 2);
  unsigned short* wqkv_bf  = (unsigned short*)carve((size_t)nWq * 2);
  unsigned short* wd_bf    = (unsigned short*)carve((size_t)H_ * H_ * 2);
  unsigned short* fused_bf = (unsigned short*)carve((size_t)B_ * S_ * H3_ * 2);
  unsigned short* z_bf     = (unsigned short*)carve((size_t)nHid * 2);
  unsigned short* ctx_bf   = (unsigned short*)carve((size_t)nHid * 2);
  float*          Gbuf     = (float*)carve((size_t)64 * 16384 * 4);
  unsigned short* ginv_bf  = (unsigned short*)carve((size_t)64 * 16384 * 2);

  // 1) bf16 casts
  cvt_bf16<<<2048, 256, 0, stream>>>(hidden, hid_bf, nHid);
  cvt_bf16<<<2048, 256, 0, stream>>>(Wqkv, wqkv_bf, nWq);
  cvt_bf16<<<2048, 256, 0, stream>>>(Wd, wd_bf, (long)H_ * H_);

  // 2) fused = hidden @ Wqkv^T + b_qkv  (bf16 out)
  gemm_bt<0><<<dim3(H3_ / 128, (B_ * S_) / 128, 1), 256, 0, stream>>>(
      hid_bf, wqkv_bf, fused_bf, bqkv, nullptr, H_, H_, H3_, H_, 0, 0, 0, 0, 0, 0);

  // 3) G = Q^T Q per (b,n); then Ginv via Gauss-Jordan (SPD)
  hipMemsetAsync(Gbuf, 0, (size_t)64 * 16384 * 4, stream);
  compute_g<<<dim3(64, 4), 256, 0, stream>>>(fused_bf, Gbuf);
  invert_g<<<64, 256, 0, stream>>>(Gbuf, ginv_bf);

  // 4) Z[b,s,n,:] = Ginv_{b,n} q_{b,n}(s)   (batched GEMM, Ginv symmetric)
  gemm_bt<2><<<dim3(1, S_ / 128, 64), 256, 0, stream>>>(
      fused_bf, ginv_bf, z_bf, nullptr, nullptr, H3_, HD_, H_, HD_,
      (long)S_ * H3_, 384, (long)32 * 16384, 16384, (long)S_ * H_, HD_);

  // 5) per-position 32x32 head attention -> ctx (bf16)
  attn_pos<<<dim3(S_, B_), 256, 0, stream>>>(fused_bf, z_bf, alibi, ctx_bf);

  // 6) out = ctx @ Wd^T + b_dense + residual  (f32 out)
  gemm_bt<1><<<dim3(H_ / 128, (B_ * S_) / 128, 1), 256, 0, stream>>>(
      ctx_bf, wd_bf, out, bd, residual, H_, H_, H_, H_, 0, 0, 0, 0, 0, 0);
}

// Round 3
// 1409.516 us; speedup vs baseline: 2.1264x; 1.1994x over previous
//
#include <hip/hip_runtime.h>

#define B_  2
#define S_  2048
#define NH_ 32
#define HD_ 128
#define H_  4096
#define H3_ 12288

typedef __bf16 bf16x8 __attribute__((ext_vector_type(8)));
typedef float  f32x4  __attribute__((ext_vector_type(4)));

__device__ __forceinline__ unsigned short f2bf(float f) {
  unsigned int u = __float_as_uint(f);
  u += 0x7fffu + ((u >> 16) & 1u);
  return (unsigned short)(u >> 16);
}
__device__ __forceinline__ void unpack8(uint4 r, float f[8]) {
  f[0] = __uint_as_float(r.x << 16); f[1] = __uint_as_float(r.x & 0xffff0000u);
  f[2] = __uint_as_float(r.y << 16); f[3] = __uint_as_float(r.y & 0xffff0000u);
  f[4] = __uint_as_float(r.z << 16); f[5] = __uint_as_float(r.z & 0xffff0000u);
  f[6] = __uint_as_float(r.w << 16); f[7] = __uint_as_float(r.w & 0xffff0000u);
}
__device__ __forceinline__ void gload_lds16(const void* g, void* l) {
  __builtin_amdgcn_global_load_lds(
      (const __attribute__((address_space(1))) unsigned int*)g,
      (__attribute__((address_space(3))) unsigned int*)l, 16, 0, 0);
}

// ---------------- f32 -> bf16 convert ----------------
__global__ __launch_bounds__(256) void cvt_bf16(const float* __restrict__ in,
                                                unsigned short* __restrict__ out,
                                                long n) {
  long i = ((long)blockIdx.x * 256 + threadIdx.x) * 4;
  const long stride = (long)gridDim.x * 256 * 4;
  for (; i < n; i += stride) {
    float4 v = *(const float4*)(in + i);
    ushort4 o;
    o.x = f2bf(v.x); o.y = f2bf(v.y); o.z = f2bf(v.z); o.w = f2bf(v.w);
    *(ushort4*)(out + i) = o;
  }
}

// =============================================================================
// 256x256-tile bf16 GEMM, C[m][n] = sum_k A[m][k]*Bt[n][k]
// 8 waves (2x4), BK=32, 3-stage LDS pipeline with counted vmcnt (never 0 in
// steady state), T2 chunk-XOR swizzle, T5 setprio around the MFMA cluster.
// EPI 0: bf16 out + bias ; EPI 1: f32 out + bias + residual
// =============================================================================
template <int EPI>
__global__ __launch_bounds__(512, 2) void gemm256(
    const unsigned short* __restrict__ A, const unsigned short* __restrict__ Bt,
    void* __restrict__ C, const float* __restrict__ bias, const float* __restrict__ Res,
    int lda, int ldb, int ldc, int K)
{
  // 3 stages x (A: 256x32 + B: 256x32) bf16 = 96 KB
  __shared__ __align__(16) unsigned short lds[3 * 16384];

  const int tid = threadIdx.x;
  const int w = tid >> 6, l = tid & 63;

  // XCD-aware block swizzle (requires nwg % 8 == 0; true for both call sites)
  const int gx = gridDim.x;
  const int nwg = gx * gridDim.y;
  const int flat = blockIdx.y * gx + blockIdx.x;
  const int swz = (flat & 7) * (nwg >> 3) + (flat >> 3);
  const int m0 = (swz / gx) * 256;
  const int n0 = (swz % gx) * 256;

  const int wr = w >> 2, wc = w & 3;      // wave output: rows wr*128.., cols wc*64..
  const int lr16 = l & 15, kq = l >> 4;

  // --- staging geometry (linear LDS dest; pre-swizzled global source) ---
  // round r covers tile rows r*128..r*128+127; wave w -> 16 rows, lane l ->
  // row (l>>2), 16B chunk (l&3). LDS chunk c of row rr holds source chunk
  // c ^ (rr&3); here rr&3 = (l>>2)&3.
  const int srow = w * 16 + (l >> 2);
  const int scs  = (((l & 3) ^ ((l >> 2) & 3)) << 3);   // source chunk, elements
  const unsigned short* ga = A  + (long)(m0 + srow) * lda + scs;
  const unsigned short* gb = Bt + (long)(n0 + srow) * ldb + scs;
  unsigned short* sb_w = lds + w * 512;                  // wave-uniform LDS base

  // --- ds_read geometry: logical chunk kq of row rr -> LDS chunk kq^(rr&3);
  // frag rows rr = base16 + (l&15) so rr&3 = l&3.
  const int rchunk = ((kq ^ (l & 3)) << 3);              // elements

  const int NT = K >> 5;

  const f32x4 zero = {0.f, 0.f, 0.f, 0.f};
  f32x4 acc[8][4];
#pragma unroll
  for (int m = 0; m < 8; ++m)
#pragma unroll
    for (int n = 0; n < 4; ++n) acc[m][n] = zero;

  auto stage = [&](int kt, int s) {
    const unsigned short* a = ga + (long)kt * 32;
    const unsigned short* b = gb + (long)kt * 32;
    unsigned short* d = sb_w + s * 16384;
    gload_lds16(a,                  d);
    gload_lds16(a + 128L * lda,     d + 4096);
    gload_lds16(b,                  d + 8192);
    gload_lds16(b + 128L * ldb,     d + 12288);
  };

  // prologue: tiles 0 and 1 in flight; wait for tile 0 only
  stage(0, 0);
  stage(1, 1);
  asm volatile("s_waitcnt vmcnt(4)" ::: "memory");
  __builtin_amdgcn_s_barrier();
  __builtin_amdgcn_sched_barrier(0);

  for (int t = 0; t < NT; ++t) {
    const int cur = t % 3;
    if (t + 2 < NT) stage(t + 2, (t + 2) % 3);

    const unsigned short* sa = lds + cur * 16384;
    const unsigned short* sbB = sa + 8192;
    bf16x8 av[8], bv[4];
#pragma unroll
    for (int n = 0; n < 4; ++n)
      bv[n] = *(const bf16x8*)&sbB[(wc * 64 + n * 16 + lr16) * 32 + rchunk];
#pragma unroll
    for (int m = 0; m < 8; ++m)
      av[m] = *(const bf16x8*)&sa[(wr * 128 + m * 16 + lr16) * 32 + rchunk];

    __builtin_amdgcn_s_setprio(1);
#pragma unroll
    for (int m = 0; m < 8; ++m)
#pragma unroll
      for (int n = 0; n < 4; ++n)
        acc[m][n] = __builtin_amdgcn_mfma_f32_16x16x32_bf16(av[m], bv[n], acc[m][n], 0, 0, 0);
    __builtin_amdgcn_s_setprio(0);

    if (t + 1 < NT) {
      // tile t+1 must be resident; the (t+2<NT ? 4 : 0) newest loads may fly on
      if (t + 2 < NT) asm volatile("s_waitcnt vmcnt(4)" ::: "memory");
      else            asm volatile("s_waitcnt vmcnt(0)" ::: "memory");
      __builtin_amdgcn_s_barrier();
      __builtin_amdgcn_sched_barrier(0);
    }
  }

  // epilogue: C/D layout col=lane&15, row=(lane>>4)*4+i
#pragma unroll
  for (int m = 0; m < 8; ++m) {
    const int grow0 = m0 + wr * 128 + m * 16 + kq * 4;
#pragma unroll
    for (int n = 0; n < 4; ++n) {
      const int gcol = n0 + wc * 64 + n * 16 + lr16;
#pragma unroll
      for (int i = 0; i < 4; ++i) {
        const long gi = (long)(grow0 + i) * ldc + gcol;
        float v = acc[m][n][i];
        if (EPI == 0) {
          ((unsigned short*)C)[gi] = f2bf(v + bias[gcol]);
        } else {
          ((float*)C)[gi] = v + bias[gcol] + Res[gi];
        }
      }
    }
  }
}

// ---------------- 128-tile bf16 GEMM (kept for the small batched Z-GEMM) -----
template <int EPI>
__global__ __launch_bounds__(256) void gemm_bt(
    const unsigned short* __restrict__ Abase, const unsigned short* __restrict__ Bbase,
    void* __restrict__ Cbase, const float* __restrict__ bias, const float* __restrict__ Res,
    int lda, int ldb, int ldc, int K,
    long sAb, long sAn, long sBb, long sBn, long sCb, long sCn)
{
  __shared__ __align__(16) unsigned short As[128][32];
  __shared__ __align__(16) unsigned short Bs[128][32];

  const int zz = blockIdx.z;
  const int zb = zz >> 5, zn = zz & 31;
  const unsigned short* A  = Abase + (long)zb * sAb + (long)zn * sAn;
  const unsigned short* Bm = Bbase + (long)zb * sBb + (long)zn * sBn;
  const long coff = (long)zb * sCb + (long)zn * sCn;

  const int m0 = blockIdx.y * 128;
  const int n0 = blockIdx.x * 128;
  const int tid = threadIdx.x;
  const int wave = tid >> 6;
  const int lane = tid & 63;
  const int wr = wave >> 1, wc = wave & 1;
  const int lr = lane & 15, kq = lane >> 4;
  const int srow = wave * 16 + (lane >> 2);
  const int scol = (lane & 3) * 8;

  const f32x4 zero = {0.0f, 0.0f, 0.0f, 0.0f};
  f32x4 acc[4][4];
#pragma unroll
  for (int m = 0; m < 4; ++m)
#pragma unroll
    for (int n = 0; n < 4; ++n) acc[m][n] = zero;

  for (int k0 = 0; k0 < K; k0 += 32) {
    const unsigned short* ga = A  + (long)(m0 + srow) * lda + k0 + scol;
    const unsigned short* gb = Bm + (long)(n0 + srow) * ldb + k0 + scol;
    gload_lds16(ga,                   &As[wave * 16][0]);
    gload_lds16(ga + (long)64 * lda,  &As[64 + wave * 16][0]);
    gload_lds16(gb,                   &Bs[wave * 16][0]);
    gload_lds16(gb + (long)64 * ldb,  &Bs[64 + wave * 16][0]);
    __syncthreads();

    bf16x8 av[4], bv[4];
#pragma unroll
    for (int m = 0; m < 4; ++m) av[m] = *(const bf16x8*)&As[wr * 64 + m * 16 + lr][kq * 8];
#pragma unroll
    for (int n = 0; n < 4; ++n) bv[n] = *(const bf16x8*)&Bs[wc * 64 + n * 16 + lr][kq * 8];
#pragma unroll
    for (int m = 0; m < 4; ++m)
#pragma unroll
      for (int n = 0; n < 4; ++n)
        acc[m][n] = __builtin_amdgcn_mfma_f32_16x16x32_bf16(av[m], bv[n], acc[m][n], 0, 0, 0);
    __syncthreads();
  }

#pragma unroll
  for (int m = 0; m < 4; ++m) {
    const int grow0 = m0 + wr * 64 + m * 16 + kq * 4;
#pragma unroll
    for (int n = 0; n < 4; ++n) {
      const int gcol = n0 + wc * 64 + n * 16 + lr;
#pragma unroll
      for (int r = 0; r < 4; ++r) {
        const long gi = coff + (long)(grow0 + r) * ldc + gcol;
        float v = acc[m][n][r];
        if (EPI == 0) {
          ((unsigned short*)Cbase)[gi] = f2bf(v + bias[gcol]);
        } else if (EPI == 1) {
          ((float*)Cbase)[gi] = v + bias[gcol] + Res[gi];
        } else {
          ((unsigned short*)Cbase)[gi] = f2bf(v);
        }
      }
    }
  }
}

// ---------------- G = Q^T Q per (b,n), chunked over s, atomic reduce ----------
__global__ __launch_bounds__(256) void compute_g(const unsigned short* __restrict__ fused,
                                                 float* __restrict__ G)
{
  __shared__ float Qs[64][128];
  const int z = blockIdx.x;            // b*32+n
  const int b = z >> 5, n = z & 31;
  const unsigned short* Q = fused + (long)b * S_ * H3_ + n * 384;
  const int t = threadIdx.x;
  const int t1 = t >> 4, t2 = t & 15;
  float acc[8][8];
#pragma unroll
  for (int a = 0; a < 8; ++a)
#pragma unroll
    for (int c = 0; c < 8; ++c) acc[a][c] = 0.f;

  const int sbeg = blockIdx.y * 512;
  for (int s0 = sbeg; s0 < sbeg + 512; s0 += 64) {
#pragma unroll
    for (int ii = 0; ii < 4; ++ii) {
      const int r = ii * 16 + t1;
      float f[8];
      unpack8(*(const uint4*)(Q + (long)(s0 + r) * H3_ + t2 * 8), f);
#pragma unroll
      for (int j = 0; j < 8; ++j) Qs[r][t2 * 8 + j] = f[j];
    }
    __syncthreads();
    for (int ss = 0; ss < 64; ++ss) {
      float qa[8], qb[8];
#pragma unroll
      for (int j = 0; j < 8; ++j) { qa[j] = Qs[ss][t1 * 8 + j]; qb[j] = Qs[ss][t2 * 8 + j]; }
#pragma unroll
      for (int a = 0; a < 8; ++a)
#pragma unroll
        for (int c = 0; c < 8; ++c) acc[a][c] += qa[a] * qb[c];
    }
    __syncthreads();
  }
  float* Gz = G + (long)z * 16384;
#pragma unroll
  for (int a = 0; a < 8; ++a)
#pragma unroll
    for (int c = 0; c < 8; ++c)
      atomicAdd(&Gz[(t1 * 8 + a) * 128 + t2 * 8 + c], acc[a][c]);
}

// ---------------- in-place Gauss-Jordan inverse of SPD 128x128 ----------------
__global__ __launch_bounds__(256) void invert_g(const float* __restrict__ G,
                                                unsigned short* __restrict__ Ginv)
{
  __shared__ float M[128][128];
  const int z = blockIdx.x;
  const int t = threadIdx.x;
  for (int idx = t; idx < 16384; idx += 256)
    M[idx >> 7][idx & 127] = G[(long)z * 16384 + idx];

  const int c  = t & 127;
  const int rh = t >> 7;
  const int rbase = rh * 64;

  for (int p = 0; p < 128; ++p) {
    __syncthreads();
    const float invp = 1.0f / M[p][p];
    float mpc = M[p][c];
    mpc = (c == p) ? invp : mpc * invp;
    float fr[64];
#pragma unroll
    for (int i = 0; i < 64; ++i) fr[i] = M[rbase + i][p];
    __syncthreads();
#pragma unroll
    for (int i = 0; i < 64; ++i) {
      const int r = rbase + i;
      if (r == p) {
        M[r][c] = mpc;
      } else {
        const float cur = (c == p) ? 0.f : M[r][c];
        M[r][c] = cur - fr[i] * mpc;
      }
    }
  }
  __syncthreads();
  for (int idx = t; idx < 16384; idx += 256)
    Ginv[(long)z * 16384 + idx] = f2bf(M[idx >> 7][idx & 127]);
}

// ---------------- per-position 32x32 head attention ----------------
__global__ __launch_bounds__(256) void attn_pos(
    const unsigned short* __restrict__ fused, const unsigned short* __restrict__ Zb,
    const float* __restrict__ alibi, unsigned short* __restrict__ ctx)
{
  __shared__ __align__(16) unsigned short qkv[H3_];
  __shared__ __align__(16) unsigned short zsh[H_];
  __shared__ float wsh[NH_][NH_ + 1];
  __shared__ float pden[NH_];
  __shared__ float alib[NH_];

  const int s = blockIdx.x, b = blockIdx.y;
  const int t = threadIdx.x;
  const unsigned short* src = fused + ((long)b * S_ + s) * H3_;
  for (int i = t * 8; i < H3_; i += 2048) *(uint4*)&qkv[i] = *(const uint4*)&src[i];
  const unsigned short* zsrc = Zb + ((long)b * S_ + s) * H_;
  for (int i = t * 8; i < H_; i += 2048) *(uint4*)&zsh[i] = *(const uint4*)&zsrc[i];
  if (t < NH_) alib[t] = 0.08838834764831845f * alibi[((long)(b * NH_ + t)) * S_ + s];
  __syncthreads();

  const int i = t >> 3;
  const int j0 = (t & 7) * 4;
  const int rot = (i ^ (t & 7)) & 15;
  float aqk[4] = {0.f, 0.f, 0.f, 0.f};
  float aqz[4] = {0.f, 0.f, 0.f, 0.f};
  for (int dbi = 0; dbi < 16; ++dbi) {
    const int d0b = ((dbi + rot) & 15) * 8;
    float qf[8];
    unpack8(*(const uint4*)&qkv[i * 384 + d0b], qf);
#pragma unroll
    for (int jj = 0; jj < 4; ++jj) {
      const int j = j0 + jj;
      float kf[8], zf[8];
      unpack8(*(const uint4*)&qkv[j * 384 + 128 + d0b], kf);
      unpack8(*(const uint4*)&zsh[j * 128 + d0b], zf);
#pragma unroll
      for (int d = 0; d < 8; ++d) { aqk[jj] += qf[d] * kf[d]; aqz[jj] += qf[d] * zf[d]; }
    }
  }
#pragma unroll
  for (int jj = 0; jj < 4; ++jj)
    wsh[i][j0 + jj] = 0.0078125f * aqk[jj] + alib[j0 + jj] * aqz[jj];
  __syncthreads();

  if (t < NH_) {
    float m = -1e30f;
    for (int j = 0; j < NH_; ++j) m = fmaxf(m, wsh[t][j]);
    float ssum = 0.f;
    for (int j = 0; j < NH_; ++j) { float e = __expf(wsh[t][j] - m); wsh[t][j] = e; ssum += e; }
    pden[t] = 1.0f / (ssum + 1e-8f);
  }
  __syncthreads();

  const int d0 = (t & 7) * 16;
  float acc[16];
#pragma unroll
  for (int d = 0; d < 16; ++d) acc[d] = 0.f;
  for (int j = 0; j < NH_; ++j) {
    const float p = wsh[i][j];
    float vf[16];
    unpack8(*(const uint4*)&qkv[j * 384 + 256 + d0], vf);
    unpack8(*(const uint4*)&qkv[j * 384 + 256 + d0 + 8], vf + 8);
#pragma unroll
    for (int d = 0; d < 16; ++d) acc[d] += p * vf[d];
  }
  const float inv = pden[i];
  union { uint4 u[2]; unsigned short us[16]; } ov;
#pragma unroll
  for (int d = 0; d < 16; ++d) ov.us[d] = f2bf(acc[d] * inv);
  unsigned short* cp = ctx + ((long)b * S_ + s) * H_ + i * HD_ + d0;
  *(uint4*)&cp[0] = ov.u[0];
  *(uint4*)&cp[8] = ov.u[1];
}

// -----------------------------------------------------------------------------
extern "C" void kernel_launch(void* const* d_in, const int* in_sizes, int n_in,
                              void* d_out, int out_size, void* d_ws, size_t ws_size,
                              hipStream_t stream)
{
  (void)in_sizes; (void)n_in; (void)out_size; (void)ws_size;
  const float* hidden   = (const float*)d_in[0];
  const float* residual = (const float*)d_in[1];
  const float* alibi    = (const float*)d_in[2];
  const float* Wqkv     = (const float*)d_in[4];
  const float* bqkv     = (const float*)d_in[5];
  const float* Wd       = (const float*)d_in[6];
  const float* bd       = (const float*)d_in[7];
  float* out = (float*)d_out;

  char* ws = (char*)d_ws;
  size_t off = 0;
  auto carve = [&](size_t bytes) -> void* {
    void* p = ws + off;
    off += (bytes + 255) & ~(size_t)255;
    return p;
  };
  const long nHid = (long)B_ * S_ * H_;
  const long nWq  = (long)H3_ * H_;
  unsigned short* hid_bf   = (unsigned short*)carve((size_t)nHid * 2);
  unsigned short* wqkv_bf  = (unsigned short*)carve((size_t)nWq * 2);
  unsigned short* wd_bf    = (unsigned short*)carve((size_t)H_ * H_ * 2);
  unsigned short* fused_bf = (unsigned short*)carve((size_t)B_ * S_ * H3_ * 2);
  unsigned short* z_bf     = (unsigned short*)carve((size_t)nHid * 2);
  unsigned short* ctx_bf   = (unsigned short*)carve((size_t)nHid * 2);
  float*          Gbuf     = (float*)carve((size_t)64 * 16384 * 4);
  unsigned short* ginv_bf  = (unsigned short*)carve((size_t)64 * 16384 * 2);

  // 1) bf16 casts
  cvt_bf16<<<2048, 256, 0, stream>>>(hidden, hid_bf, nHid);
  cvt_bf16<<<2048, 256, 0, stream>>>(Wqkv, wqkv_bf, nWq);
  cvt_bf16<<<2048, 256, 0, stream>>>(Wd, wd_bf, (long)H_ * H_);

  // 2) fused = hidden @ Wqkv^T + b_qkv  (bf16 out) — 256² pipelined GEMM
  gemm256<0><<<dim3(H3_ / 256, (B_ * S_) / 256, 1), 512, 0, stream>>>(
      hid_bf, wqkv_bf, fused_bf, bqkv, nullptr, H_, H_, H3_, H_);

  // 3) G = Q^T Q per (b,n); then Ginv via Gauss-Jordan (SPD)
  hipMemsetAsync(Gbuf, 0, (size_t)64 * 16384 * 4, stream);
  compute_g<<<dim3(64, 4), 256, 0, stream>>>(fused_bf, Gbuf);
  invert_g<<<64, 256, 0, stream>>>(Gbuf, ginv_bf);

  // 4) Z[b,s,n,:] = Ginv_{b,n} q_{b,n}(s)   (small batched GEMM, 128² kernel)
  gemm_bt<2><<<dim3(1, S_ / 128, 64), 256, 0, stream>>>(
      fused_bf, ginv_bf, z_bf, nullptr, nullptr, H3_, HD_, H_, HD_,
      (long)S_ * H3_, 384, (long)32 * 16384, 16384, (long)S_ * H_, HD_);

  // 5) per-position 32x32 head attention -> ctx (bf16)
  attn_pos<<<dim3(S_, B_), 256, 0, stream>>>(fused_bf, z_bf, alibi, ctx_bf);

  // 6) out = ctx @ Wd^T + b_dense + residual  (f32 out) — 256² pipelined GEMM
  gemm256<1><<<dim3(H_ / 256, (B_ * S_) / 256, 1), 512, 0, stream>>>(
      ctx_bf, wd_bf, out, bd, residual, H_, H_, H_, H_);
}

// Round 4
// 980.963 us; speedup vs baseline: 3.0554x; 1.4369x over previous
//
#include <hip/hip_runtime.h>

#define B_  2
#define S_  2048
#define NH_ 32
#define HD_ 128
#define H_  4096
#define H3_ 12288

typedef __bf16 bf16x8 __attribute__((ext_vector_type(8)));
typedef float  f32x4  __attribute__((ext_vector_type(4)));

__device__ __forceinline__ unsigned short f2bf(float f) {
  unsigned int u = __float_as_uint(f);
  u += 0x7fffu + ((u >> 16) & 1u);
  return (unsigned short)(u >> 16);
}
__device__ __forceinline__ void unpack8(uint4 r, float f[8]) {
  f[0] = __uint_as_float(r.x << 16); f[1] = __uint_as_float(r.x & 0xffff0000u);
  f[2] = __uint_as_float(r.y << 16); f[3] = __uint_as_float(r.y & 0xffff0000u);
  f[4] = __uint_as_float(r.z << 16); f[5] = __uint_as_float(r.z & 0xffff0000u);
  f[6] = __uint_as_float(r.w << 16); f[7] = __uint_as_float(r.w & 0xffff0000u);
}
__device__ __forceinline__ void gload_lds16(const void* g, void* l) {
  __builtin_amdgcn_global_load_lds(
      (const __attribute__((address_space(1))) unsigned int*)g,
      (__attribute__((address_space(3))) unsigned int*)l, 16, 0, 0);
}

// ---------------- f32 -> bf16 convert ----------------
__global__ __launch_bounds__(256) void cvt_bf16(const float* __restrict__ in,
                                                unsigned short* __restrict__ out,
                                                long n) {
  long i = ((long)blockIdx.x * 256 + threadIdx.x) * 4;
  const long stride = (long)gridDim.x * 256 * 4;
  for (; i < n; i += stride) {
    float4 v = *(const float4*)(in + i);
    ushort4 o;
    o.x = f2bf(v.x); o.y = f2bf(v.y); o.z = f2bf(v.z); o.w = f2bf(v.w);
    *(ushort4*)(out + i) = o;
  }
}

// =============================================================================
// 256x256-tile bf16 GEMM, C[m][n] = sum_k A[m][k]*Bt[n][k]
// 8 waves (2x4), BK=32, 3-stage LDS pipeline with counted vmcnt (never 0 in
// steady state), T2 chunk-XOR swizzle, T5 setprio around the MFMA cluster.
// EPI 0: bf16 out + bias ; EPI 1: f32 out + bias + residual
// =============================================================================
template <int EPI>
__global__ __launch_bounds__(512, 2) void gemm256(
    const unsigned short* __restrict__ A, const unsigned short* __restrict__ Bt,
    void* __restrict__ C, const float* __restrict__ bias, const float* __restrict__ Res,
    int lda, int ldb, int ldc, int K)
{
  // 3 stages x (A: 256x32 + B: 256x32) bf16 = 96 KB
  __shared__ __align__(16) unsigned short lds[3 * 16384];

  const int tid = threadIdx.x;
  const int w = tid >> 6, l = tid & 63;

  // XCD-aware block swizzle (requires nwg % 8 == 0; true for both call sites)
  const int gx = gridDim.x;
  const int nwg = gx * gridDim.y;
  const int flat = blockIdx.y * gx + blockIdx.x;
  const int swz = (flat & 7) * (nwg >> 3) + (flat >> 3);
  const int m0 = (swz / gx) * 256;
  const int n0 = (swz % gx) * 256;

  const int wr = w >> 2, wc = w & 3;      // wave output: rows wr*128.., cols wc*64..
  const int lr16 = l & 15, kq = l >> 4;

  // --- staging geometry (linear LDS dest; pre-swizzled global source) ---
  const int srow = w * 16 + (l >> 2);
  const int scs  = (((l & 3) ^ ((l >> 2) & 3)) << 3);   // source chunk, elements
  const unsigned short* ga = A  + (long)(m0 + srow) * lda + scs;
  const unsigned short* gb = Bt + (long)(n0 + srow) * ldb + scs;
  unsigned short* sb_w = lds + w * 512;                  // wave-uniform LDS base

  // --- ds_read geometry: logical chunk kq of row rr -> LDS chunk kq^(rr&3)
  const int rchunk = ((kq ^ (l & 3)) << 3);              // elements

  const int NT = K >> 5;

  const f32x4 zero = {0.f, 0.f, 0.f, 0.f};
  f32x4 acc[8][4];
#pragma unroll
  for (int m = 0; m < 8; ++m)
#pragma unroll
    for (int n = 0; n < 4; ++n) acc[m][n] = zero;

  auto stage = [&](int kt, int s) {
    const unsigned short* a = ga + (long)kt * 32;
    const unsigned short* b = gb + (long)kt * 32;
    unsigned short* d = sb_w + s * 16384;
    gload_lds16(a,                  d);
    gload_lds16(a + 128L * lda,     d + 4096);
    gload_lds16(b,                  d + 8192);
    gload_lds16(b + 128L * ldb,     d + 12288);
  };

  // prologue: tiles 0 and 1 in flight; wait for tile 0 only
  stage(0, 0);
  stage(1, 1);
  asm volatile("s_waitcnt vmcnt(4)" ::: "memory");
  __builtin_amdgcn_s_barrier();
  __builtin_amdgcn_sched_barrier(0);

  for (int t = 0; t < NT; ++t) {
    const int cur = t % 3;
    if (t + 2 < NT) stage(t + 2, (t + 2) % 3);

    const unsigned short* sa = lds + cur * 16384;
    const unsigned short* sbB = sa + 8192;
    bf16x8 av[8], bv[4];
#pragma unroll
    for (int n = 0; n < 4; ++n)
      bv[n] = *(const bf16x8*)&sbB[(wc * 64 + n * 16 + lr16) * 32 + rchunk];
#pragma unroll
    for (int m = 0; m < 8; ++m)
      av[m] = *(const bf16x8*)&sa[(wr * 128 + m * 16 + lr16) * 32 + rchunk];

    __builtin_amdgcn_s_setprio(1);
#pragma unroll
    for (int m = 0; m < 8; ++m)
#pragma unroll
      for (int n = 0; n < 4; ++n)
        acc[m][n] = __builtin_amdgcn_mfma_f32_16x16x32_bf16(av[m], bv[n], acc[m][n], 0, 0, 0);
    __builtin_amdgcn_s_setprio(0);

    if (t + 1 < NT) {
      if (t + 2 < NT) asm volatile("s_waitcnt vmcnt(4)" ::: "memory");
      else            asm volatile("s_waitcnt vmcnt(0)" ::: "memory");
      __builtin_amdgcn_s_barrier();
      __builtin_amdgcn_sched_barrier(0);
    }
  }

  // epilogue: C/D layout col=lane&15, row=(lane>>4)*4+i
#pragma unroll
  for (int m = 0; m < 8; ++m) {
    const int grow0 = m0 + wr * 128 + m * 16 + kq * 4;
#pragma unroll
    for (int n = 0; n < 4; ++n) {
      const int gcol = n0 + wc * 64 + n * 16 + lr16;
#pragma unroll
      for (int i = 0; i < 4; ++i) {
        const long gi = (long)(grow0 + i) * ldc + gcol;
        float v = acc[m][n][i];
        if (EPI == 0) {
          ((unsigned short*)C)[gi] = f2bf(v + bias[gcol]);
        } else {
          ((float*)C)[gi] = v + bias[gcol] + Res[gi];
        }
      }
    }
  }
}

// ---------------- 128-tile bf16 GEMM (kept for the small batched Z-GEMM) -----
template <int EPI>
__global__ __launch_bounds__(256) void gemm_bt(
    const unsigned short* __restrict__ Abase, const unsigned short* __restrict__ Bbase,
    void* __restrict__ Cbase, const float* __restrict__ bias, const float* __restrict__ Res,
    int lda, int ldb, int ldc, int K,
    long sAb, long sAn, long sBb, long sBn, long sCb, long sCn)
{
  __shared__ __align__(16) unsigned short As[128][32];
  __shared__ __align__(16) unsigned short Bs[128][32];

  const int zz = blockIdx.z;
  const int zb = zz >> 5, zn = zz & 31;
  const unsigned short* A  = Abase + (long)zb * sAb + (long)zn * sAn;
  const unsigned short* Bm = Bbase + (long)zb * sBb + (long)zn * sBn;
  const long coff = (long)zb * sCb + (long)zn * sCn;

  const int m0 = blockIdx.y * 128;
  const int n0 = blockIdx.x * 128;
  const int tid = threadIdx.x;
  const int wave = tid >> 6;
  const int lane = tid & 63;
  const int wr = wave >> 1, wc = wave & 1;
  const int lr = lane & 15, kq = lane >> 4;
  const int srow = wave * 16 + (lane >> 2);
  const int scol = (lane & 3) * 8;

  const f32x4 zero = {0.0f, 0.0f, 0.0f, 0.0f};
  f32x4 acc[4][4];
#pragma unroll
  for (int m = 0; m < 4; ++m)
#pragma unroll
    for (int n = 0; n < 4; ++n) acc[m][n] = zero;

  for (int k0 = 0; k0 < K; k0 += 32) {
    const unsigned short* ga = A  + (long)(m0 + srow) * lda + k0 + scol;
    const unsigned short* gb = Bm + (long)(n0 + srow) * ldb + k0 + scol;
    gload_lds16(ga,                   &As[wave * 16][0]);
    gload_lds16(ga + (long)64 * lda,  &As[64 + wave * 16][0]);
    gload_lds16(gb,                   &Bs[wave * 16][0]);
    gload_lds16(gb + (long)64 * ldb,  &Bs[64 + wave * 16][0]);
    __syncthreads();

    bf16x8 av[4], bv[4];
#pragma unroll
    for (int m = 0; m < 4; ++m) av[m] = *(const bf16x8*)&As[wr * 64 + m * 16 + lr][kq * 8];
#pragma unroll
    for (int n = 0; n < 4; ++n) bv[n] = *(const bf16x8*)&Bs[wc * 64 + n * 16 + lr][kq * 8];
#pragma unroll
    for (int m = 0; m < 4; ++m)
#pragma unroll
      for (int n = 0; n < 4; ++n)
        acc[m][n] = __builtin_amdgcn_mfma_f32_16x16x32_bf16(av[m], bv[n], acc[m][n], 0, 0, 0);
    __syncthreads();
  }

#pragma unroll
  for (int m = 0; m < 4; ++m) {
    const int grow0 = m0 + wr * 64 + m * 16 + kq * 4;
#pragma unroll
    for (int n = 0; n < 4; ++n) {
      const int gcol = n0 + wc * 64 + n * 16 + lr;
#pragma unroll
      for (int r = 0; r < 4; ++r) {
        const long gi = coff + (long)(grow0 + r) * ldc + gcol;
        float v = acc[m][n][r];
        if (EPI == 0) {
          ((unsigned short*)Cbase)[gi] = f2bf(v + bias[gcol]);
        } else if (EPI == 1) {
          ((float*)Cbase)[gi] = v + bias[gcol] + Res[gi];
        } else {
          ((unsigned short*)Cbase)[gi] = f2bf(v);
        }
      }
    }
  }
}

// ---------------- G = Q^T Q per (b,n), chunked over s, atomic reduce ----------
__global__ __launch_bounds__(256) void compute_g(const unsigned short* __restrict__ fused,
                                                 float* __restrict__ G)
{
  __shared__ float Qs[64][128];
  const int z = blockIdx.x;            // b*32+n
  const int b = z >> 5, n = z & 31;
  const unsigned short* Q = fused + (long)b * S_ * H3_ + n * 384;
  const int t = threadIdx.x;
  const int t1 = t >> 4, t2 = t & 15;
  float acc[8][8];
#pragma unroll
  for (int a = 0; a < 8; ++a)
#pragma unroll
    for (int c = 0; c < 8; ++c) acc[a][c] = 0.f;

  const int sbeg = blockIdx.y * 512;
  for (int s0 = sbeg; s0 < sbeg + 512; s0 += 64) {
#pragma unroll
    for (int ii = 0; ii < 4; ++ii) {
      const int r = ii * 16 + t1;
      float f[8];
      unpack8(*(const uint4*)(Q + (long)(s0 + r) * H3_ + t2 * 8), f);
#pragma unroll
      for (int j = 0; j < 8; ++j) Qs[r][t2 * 8 + j] = f[j];
    }
    __syncthreads();
    for (int ss = 0; ss < 64; ++ss) {
      float qa[8], qb[8];
#pragma unroll
      for (int j = 0; j < 8; ++j) { qa[j] = Qs[ss][t1 * 8 + j]; qb[j] = Qs[ss][t2 * 8 + j]; }
#pragma unroll
      for (int a = 0; a < 8; ++a)
#pragma unroll
        for (int c = 0; c < 8; ++c) acc[a][c] += qa[a] * qb[c];
    }
    __syncthreads();
  }
  float* Gz = G + (long)z * 16384;
#pragma unroll
  for (int a = 0; a < 8; ++a)
#pragma unroll
    for (int c = 0; c < 8; ++c)
      atomicAdd(&Gz[(t1 * 8 + a) * 128 + t2 * 8 + c], acc[a][c]);
}

// ---------------- register-resident Gauss-Jordan inverse of SPD 128x128 ------
// 1024 threads: thread (c = t&127, rg = t>>7) owns M[rg*16 .. rg*16+15][c] in
// 16 VGPRs (all indices compile-time; rule #20). LDS holds only the pivot row
// and pivot column (double-buffered -> ONE barrier per pivot). Pivot-column
// reads are wave-broadcast b128; pivot-row read is lane-consecutive.
__global__ __launch_bounds__(1024) void invert_g(const float* __restrict__ G,
                                                 unsigned short* __restrict__ Ginv)
{
  __shared__ __align__(16) float prow[2][128];
  __shared__ __align__(16) float pcol[2][128];
  const int z = blockIdx.x;
  const int t = threadIdx.x;
  const int c  = t & 127;
  const int rg = t >> 7;                 // 0..7 -> rows rg*16 .. rg*16+15
  const float* Gz = G + (long)z * 16384;

  float a[16];
#pragma unroll
  for (int i = 0; i < 16; ++i) a[i] = Gz[(rg * 16 + i) * 128 + c];

  for (int p = 0; p < 128; ++p) {
    const int buf = p & 1;
    const int prg = p >> 4, pi = p & 15;
    // publish pivot row (owned by rg==prg threads) via static register select
    if (rg == prg) {
      float v = a[0];
#pragma unroll
      for (int i = 1; i < 16; ++i) v = (pi == i) ? a[i] : v;
      prow[buf][c] = v;
    }
    // publish pivot column (owned by the c==p thread of each rg)
    if (c == p) {
#pragma unroll
      for (int q = 0; q < 4; ++q) {
        float4 w4 = make_float4(a[q * 4], a[q * 4 + 1], a[q * 4 + 2], a[q * 4 + 3]);
        *(float4*)&pcol[buf][rg * 16 + q * 4] = w4;
      }
    }
    __syncthreads();
    const float invp = 1.0f / prow[buf][p];          // broadcast
    const float rowv = (c == p) ? invp : prow[buf][c] * invp;
#pragma unroll
    for (int q = 0; q < 4; ++q) {
      const float4 pc4 = *(const float4*)&pcol[buf][rg * 16 + q * 4];  // broadcast
      const float pcv[4] = {pc4.x, pc4.y, pc4.z, pc4.w};
#pragma unroll
      for (int j = 0; j < 4; ++j) {
        const int i = q * 4 + j;
        const int r = rg * 16 + i;
        const float cur = (c == p) ? 0.f : a[i];
        a[i] = (r == p) ? rowv : cur - pcv[j] * rowv;
      }
    }
    // no second barrier: next pivot writes buf^1; buf^1's previous readers are
    // ordered before this pivot's barrier.
  }
  unsigned short* Oz = Ginv + (long)z * 16384;
#pragma unroll
  for (int i = 0; i < 16; ++i) Oz[(rg * 16 + i) * 128 + c] = f2bf(a[i]);
}

// ---------------- per-position 32x32 head attention ----------------
__global__ __launch_bounds__(256) void attn_pos(
    const unsigned short* __restrict__ fused, const unsigned short* __restrict__ Zb,
    const float* __restrict__ alibi, unsigned short* __restrict__ ctx)
{
  __shared__ __align__(16) unsigned short qkv[H3_];
  __shared__ __align__(16) unsigned short zsh[H_];
  __shared__ float wsh[NH_][NH_ + 1];
  __shared__ float pden[NH_];
  __shared__ float alib[NH_];

  const int s = blockIdx.x, b = blockIdx.y;
  const int t = threadIdx.x;
  const unsigned short* src = fused + ((long)b * S_ + s) * H3_;
  for (int i = t * 8; i < H3_; i += 2048) *(uint4*)&qkv[i] = *(const uint4*)&src[i];
  const unsigned short* zsrc = Zb + ((long)b * S_ + s) * H_;
  for (int i = t * 8; i < H_; i += 2048) *(uint4*)&zsh[i] = *(const uint4*)&zsrc[i];
  if (t < NH_) alib[t] = 0.08838834764831845f * alibi[((long)(b * NH_ + t)) * S_ + s];
  __syncthreads();

  const int i = t >> 3;
  const int j0 = (t & 7) * 4;
  const int rot = (i ^ (t & 7)) & 15;
  float aqk[4] = {0.f, 0.f, 0.f, 0.f};
  float aqz[4] = {0.f, 0.f, 0.f, 0.f};
  for (int dbi = 0; dbi < 16; ++dbi) {
    const int d0b = ((dbi + rot) & 15) * 8;
    float qf[8];
    unpack8(*(const uint4*)&qkv[i * 384 + d0b], qf);
#pragma unroll
    for (int jj = 0; jj < 4; ++jj) {
      const int j = j0 + jj;
      float kf[8], zf[8];
      unpack8(*(const uint4*)&qkv[j * 384 + 128 + d0b], kf);
      unpack8(*(const uint4*)&zsh[j * 128 + d0b], zf);
#pragma unroll
      for (int d = 0; d < 8; ++d) { aqk[jj] += qf[d] * kf[d]; aqz[jj] += qf[d] * zf[d]; }
    }
  }
#pragma unroll
  for (int jj = 0; jj < 4; ++jj)
    wsh[i][j0 + jj] = 0.0078125f * aqk[jj] + alib[j0 + jj] * aqz[jj];
  __syncthreads();

  if (t < NH_) {
    float m = -1e30f;
    for (int j = 0; j < NH_; ++j) m = fmaxf(m, wsh[t][j]);
    float ssum = 0.f;
    for (int j = 0; j < NH_; ++j) { float e = __expf(wsh[t][j] - m); wsh[t][j] = e; ssum += e; }
    pden[t] = 1.0f / (ssum + 1e-8f);
  }
  __syncthreads();

  const int d0 = (t & 7) * 16;
  float acc[16];
#pragma unroll
  for (int d = 0; d < 16; ++d) acc[d] = 0.f;
  for (int j = 0; j < NH_; ++j) {
    const float p = wsh[i][j];
    float vf[16];
    unpack8(*(const uint4*)&qkv[j * 384 + 256 + d0], vf);
    unpack8(*(const uint4*)&qkv[j * 384 + 256 + d0 + 8], vf + 8);
#pragma unroll
    for (int d = 0; d < 16; ++d) acc[d] += p * vf[d];
  }
  const float inv = pden[i];
  union { uint4 u[2]; unsigned short us[16]; } ov;
#pragma unroll
  for (int d = 0; d < 16; ++d) ov.us[d] = f2bf(acc[d] * inv);
  unsigned short* cp = ctx + ((long)b * S_ + s) * H_ + i * HD_ + d0;
  *(uint4*)&cp[0] = ov.u[0];
  *(uint4*)&cp[8] = ov.u[1];
}

// -----------------------------------------------------------------------------
extern "C" void kernel_launch(void* const* d_in, const int* in_sizes, int n_in,
                              void* d_out, int out_size, void* d_ws, size_t ws_size,
                              hipStream_t stream)
{
  (void)in_sizes; (void)n_in; (void)out_size; (void)ws_size;
  const float* hidden   = (const float*)d_in[0];
  const float* residual = (const float*)d_in[1];
  const float* alibi    = (const float*)d_in[2];
  const float* Wqkv     = (const float*)d_in[4];
  const float* bqkv     = (const float*)d_in[5];
  const float* Wd       = (const float*)d_in[6];
  const float* bd       = (const float*)d_in[7];
  float* out = (float*)d_out;

  char* ws = (char*)d_ws;
  size_t off = 0;
  auto carve = [&](size_t bytes) -> void* {
    void* p = ws + off;
    off += (bytes + 255) & ~(size_t)255;
    return p;
  };
  const long nHid = (long)B_ * S_ * H_;
  const long nWq  = (long)H3_ * H_;
  unsigned short* hid_bf   = (unsigned short*)carve((size_t)nHid * 2);
  unsigned short* wqkv_bf  = (unsigned short*)carve((size_t)nWq * 2);
  unsigned short* wd_bf    = (unsigned short*)carve((size_t)H_ * H_ * 2);
  unsigned short* fused_bf = (unsigned short*)carve((size_t)B_ * S_ * H3_ * 2);
  unsigned short* z_bf     = (unsigned short*)carve((size_t)nHid * 2);
  unsigned short* ctx_bf   = (unsigned short*)carve((size_t)nHid * 2);
  float*          Gbuf     = (float*)carve((size_t)64 * 16384 * 4);
  unsigned short* ginv_bf  = (unsigned short*)carve((size_t)64 * 16384 * 2);

  // 1) bf16 casts
  cvt_bf16<<<2048, 256, 0, stream>>>(hidden, hid_bf, nHid);
  cvt_bf16<<<2048, 256, 0, stream>>>(Wqkv, wqkv_bf, nWq);
  cvt_bf16<<<2048, 256, 0, stream>>>(Wd, wd_bf, (long)H_ * H_);

  // 2) fused = hidden @ Wqkv^T + b_qkv  (bf16 out) — 256² pipelined GEMM
  gemm256<0><<<dim3(H3_ / 256, (B_ * S_) / 256, 1), 512, 0, stream>>>(
      hid_bf, wqkv_bf, fused_bf, bqkv, nullptr, H_, H_, H3_, H_);

  // 3) G = Q^T Q per (b,n); then Ginv via register-resident Gauss-Jordan
  hipMemsetAsync(Gbuf, 0, (size_t)64 * 16384 * 4, stream);
  compute_g<<<dim3(64, 4), 256, 0, stream>>>(fused_bf, Gbuf);
  invert_g<<<64, 1024, 0, stream>>>(Gbuf, ginv_bf);

  // 4) Z[b,s,n,:] = Ginv_{b,n} q_{b,n}(s)   (small batched GEMM, 128² kernel)
  gemm_bt<2><<<dim3(1, S_ / 128, 64), 256, 0, stream>>>(
      fused_bf, ginv_bf, z_bf, nullptr, nullptr, H3_, HD_, H_, HD_,
      (long)S_ * H3_, 384, (long)32 * 16384, 16384, (long)S_ * H_, HD_);

  // 5) per-position 32x32 head attention -> ctx (bf16)
  attn_pos<<<dim3(S_, B_), 256, 0, stream>>>(fused_bf, z_bf, alibi, ctx_bf);

  // 6) out = ctx @ Wd^T + b_dense + residual  (f32 out) — 256² pipelined GEMM
  gemm256<1><<<dim3(H_ / 256, (B_ * S_) / 256, 1), 512, 0, stream>>>(
      ctx_bf, wd_bf, out, bd, residual, H_, H_, H_, H_);
}

// Round 5
// 961.456 us; speedup vs baseline: 3.1174x; 1.0203x over previous
//
#include <hip/hip_runtime.h>

#define B_  2
#define S_  2048
#define NH_ 32
#define HD_ 128
#define H_  4096
#define H3_ 12288

typedef __bf16 bf16x8 __attribute__((ext_vector_type(8)));
typedef float  f32x4  __attribute__((ext_vector_type(4)));

__device__ __forceinline__ unsigned short f2bf(float f) {
  unsigned int u = __float_as_uint(f);
  u += 0x7fffu + ((u >> 16) & 1u);
  return (unsigned short)(u >> 16);
}
__device__ __forceinline__ void unpack8(uint4 r, float f[8]) {
  f[0] = __uint_as_float(r.x << 16); f[1] = __uint_as_float(r.x & 0xffff0000u);
  f[2] = __uint_as_float(r.y << 16); f[3] = __uint_as_float(r.y & 0xffff0000u);
  f[4] = __uint_as_float(r.z << 16); f[5] = __uint_as_float(r.z & 0xffff0000u);
  f[6] = __uint_as_float(r.w << 16); f[7] = __uint_as_float(r.w & 0xffff0000u);
}
__device__ __forceinline__ void gload_lds16(const void* g, void* l) {
  __builtin_amdgcn_global_load_lds(
      (const __attribute__((address_space(1))) unsigned int*)g,
      (__attribute__((address_space(3))) unsigned int*)l, 16, 0, 0);
}

// ---------------- f32 -> bf16 convert ----------------
__global__ __launch_bounds__(256) void cvt_bf16(const float* __restrict__ in,
                                                unsigned short* __restrict__ out,
                                                long n) {
  long i = ((long)blockIdx.x * 256 + threadIdx.x) * 4;
  const long stride = (long)gridDim.x * 256 * 4;
  for (; i < n; i += stride) {
    float4 v = *(const float4*)(in + i);
    ushort4 o;
    o.x = f2bf(v.x); o.y = f2bf(v.y); o.z = f2bf(v.z); o.w = f2bf(v.w);
    *(ushort4*)(out + i) = o;
  }
}

// =============================================================================
// 256x256-tile bf16 GEMM, C[m][n] = sum_k A[m][k]*Bt[n][k]
// 8 waves (2x4), BK=32, 3-stage LDS pipeline with counted vmcnt, T2 swizzle
// (chunk ^= row bits 1..2 -> 8x16B slot classes, 2 lanes/bank), T5 setprio.
// EPI 0: bf16 out + bias ; EPI 1: f32 out + bias + residual
// =============================================================================
template <int EPI>
__global__ __launch_bounds__(512, 2) void gemm256(
    const unsigned short* __restrict__ A, const unsigned short* __restrict__ Bt,
    void* __restrict__ C, const float* __restrict__ bias, const float* __restrict__ Res,
    int lda, int ldb, int ldc, int K)
{
  // 3 stages x (A: 256x32 + B: 256x32) bf16 = 96 KB
  __shared__ __align__(16) unsigned short lds[3 * 16384];

  const int tid = threadIdx.x;
  const int w = tid >> 6, l = tid & 63;

  // XCD-aware block swizzle (requires nwg % 8 == 0; true for both call sites)
  const int gx = gridDim.x;
  const int nwg = gx * gridDim.y;
  const int flat = blockIdx.y * gx + blockIdx.x;
  const int swz = (flat & 7) * (nwg >> 3) + (flat >> 3);
  const int m0 = (swz / gx) * 256;
  const int n0 = (swz % gx) * 256;

  const int wr = w >> 2, wc = w & 3;      // wave output: rows wr*128.., cols wc*64..
  const int lr16 = l & 15, kq = l >> 4;

  // --- staging geometry (linear LDS dest; pre-swizzled global source) ---
  // lane l stages row r=(l>>2) of its 16-row group into physical chunk (l&3);
  // physical chunk pc of row r holds source chunk pc ^ ((r>>1)&3) = pc ^ ((l>>3)&3)
  const int srow = w * 16 + (l >> 2);
  const int scs  = (((l & 3) ^ ((l >> 3) & 3)) << 3);   // source chunk, elements
  const unsigned short* ga = A  + (long)(m0 + srow) * lda + scs;
  const unsigned short* gb = Bt + (long)(n0 + srow) * ldb + scs;
  unsigned short* sb_w = lds + w * 512;                  // wave-uniform LDS base

  // --- ds_read: logical chunk kq of row rr lives at physical chunk kq^((rr>>1)&3);
  // fragment rows rr = base16 + (l&15) so (rr>>1)&3 = (l>>1)&3.
  const int rchunk = ((kq ^ ((l >> 1) & 3)) << 3);       // elements

  const int NT = K >> 5;

  const f32x4 zero = {0.f, 0.f, 0.f, 0.f};
  f32x4 acc[8][4];
#pragma unroll
  for (int m = 0; m < 8; ++m)
#pragma unroll
    for (int n = 0; n < 4; ++n) acc[m][n] = zero;

  auto stage = [&](int kt, int s) {
    const unsigned short* a = ga + (long)kt * 32;
    const unsigned short* b = gb + (long)kt * 32;
    unsigned short* d = sb_w + s * 16384;
    gload_lds16(a,                  d);
    gload_lds16(a + 128L * lda,     d + 4096);
    gload_lds16(b,                  d + 8192);
    gload_lds16(b + 128L * ldb,     d + 12288);
  };

  // prologue: tiles 0 and 1 in flight; wait for tile 0 only
  stage(0, 0);
  stage(1, 1);
  asm volatile("s_waitcnt vmcnt(4)" ::: "memory");
  __builtin_amdgcn_s_barrier();
  __builtin_amdgcn_sched_barrier(0);

  for (int t = 0; t < NT; ++t) {
    const int cur = t % 3;
    if (t + 2 < NT) stage(t + 2, (t + 2) % 3);

    const unsigned short* sa = lds + cur * 16384;
    const unsigned short* sbB = sa + 8192;
    bf16x8 av[8], bv[4];
#pragma unroll
    for (int n = 0; n < 4; ++n)
      bv[n] = *(const bf16x8*)&sbB[(wc * 64 + n * 16 + lr16) * 32 + rchunk];
#pragma unroll
    for (int m = 0; m < 8; ++m)
      av[m] = *(const bf16x8*)&sa[(wr * 128 + m * 16 + lr16) * 32 + rchunk];

    __builtin_amdgcn_s_setprio(1);
#pragma unroll
    for (int m = 0; m < 8; ++m)
#pragma unroll
      for (int n = 0; n < 4; ++n)
        acc[m][n] = __builtin_amdgcn_mfma_f32_16x16x32_bf16(av[m], bv[n], acc[m][n], 0, 0, 0);
    __builtin_amdgcn_s_setprio(0);

    if (t + 1 < NT) {
      if (t + 2 < NT) asm volatile("s_waitcnt vmcnt(4)" ::: "memory");
      else            asm volatile("s_waitcnt vmcnt(0)" ::: "memory");
      __builtin_amdgcn_s_barrier();
      __builtin_amdgcn_sched_barrier(0);
    }
  }

  // epilogue: C/D layout col=lane&15, row=(lane>>4)*4+i
#pragma unroll
  for (int m = 0; m < 8; ++m) {
    const int grow0 = m0 + wr * 128 + m * 16 + kq * 4;
#pragma unroll
    for (int n = 0; n < 4; ++n) {
      const int gcol = n0 + wc * 64 + n * 16 + lr16;
#pragma unroll
      for (int i = 0; i < 4; ++i) {
        const long gi = (long)(grow0 + i) * ldc + gcol;
        float v = acc[m][n][i];
        if (EPI == 0) {
          ((unsigned short*)C)[gi] = f2bf(v + bias[gcol]);
        } else {
          ((float*)C)[gi] = v + bias[gcol] + Res[gi];
        }
      }
    }
  }
}

// ---------------- 128-tile bf16 GEMM (batched Z-GEMM), same swizzle ----------
template <int EPI>
__global__ __launch_bounds__(256) void gemm_bt(
    const unsigned short* __restrict__ Abase, const unsigned short* __restrict__ Bbase,
    void* __restrict__ Cbase, const float* __restrict__ bias, const float* __restrict__ Res,
    int lda, int ldb, int ldc, int K,
    long sAb, long sAn, long sBb, long sBn, long sCb, long sCn)
{
  __shared__ __align__(16) unsigned short As[128][32];
  __shared__ __align__(16) unsigned short Bs[128][32];

  const int zz = blockIdx.z;
  const int zb = zz >> 5, zn = zz & 31;
  const unsigned short* A  = Abase + (long)zb * sAb + (long)zn * sAn;
  const unsigned short* Bm = Bbase + (long)zb * sBb + (long)zn * sBn;
  const long coff = (long)zb * sCb + (long)zn * sCn;

  const int m0 = blockIdx.y * 128;
  const int n0 = blockIdx.x * 128;
  const int tid = threadIdx.x;
  const int wave = tid >> 6;
  const int lane = tid & 63;
  const int wr = wave >> 1, wc = wave & 1;
  const int lr = lane & 15, kq = lane >> 4;
  const int srow = wave * 16 + (lane >> 2);
  const int scol = (((lane & 3) ^ ((lane >> 3) & 3)) << 3);  // swizzled source chunk
  const int rch  = ((kq ^ ((lane >> 1) & 3)) << 3);          // swizzled read chunk

  const f32x4 zero = {0.0f, 0.0f, 0.0f, 0.0f};
  f32x4 acc[4][4];
#pragma unroll
  for (int m = 0; m < 4; ++m)
#pragma unroll
    for (int n = 0; n < 4; ++n) acc[m][n] = zero;

  for (int k0 = 0; k0 < K; k0 += 32) {
    const unsigned short* ga = A  + (long)(m0 + srow) * lda + k0 + scol;
    const unsigned short* gb = Bm + (long)(n0 + srow) * ldb + k0 + scol;
    gload_lds16(ga,                   &As[wave * 16][0]);
    gload_lds16(ga + (long)64 * lda,  &As[64 + wave * 16][0]);
    gload_lds16(gb,                   &Bs[wave * 16][0]);
    gload_lds16(gb + (long)64 * ldb,  &Bs[64 + wave * 16][0]);
    __syncthreads();

    bf16x8 av[4], bv[4];
#pragma unroll
    for (int m = 0; m < 4; ++m) av[m] = *(const bf16x8*)&As[wr * 64 + m * 16 + lr][rch];
#pragma unroll
    for (int n = 0; n < 4; ++n) bv[n] = *(const bf16x8*)&Bs[wc * 64 + n * 16 + lr][rch];
#pragma unroll
    for (int m = 0; m < 4; ++m)
#pragma unroll
      for (int n = 0; n < 4; ++n)
        acc[m][n] = __builtin_amdgcn_mfma_f32_16x16x32_bf16(av[m], bv[n], acc[m][n], 0, 0, 0);
    __syncthreads();
  }

#pragma unroll
  for (int m = 0; m < 4; ++m) {
    const int grow0 = m0 + wr * 64 + m * 16 + kq * 4;
#pragma unroll
    for (int n = 0; n < 4; ++n) {
      const int gcol = n0 + wc * 64 + n * 16 + lr;
#pragma unroll
      for (int r = 0; r < 4; ++r) {
        const long gi = coff + (long)(grow0 + r) * ldc + gcol;
        float v = acc[m][n][r];
        if (EPI == 0) {
          ((unsigned short*)Cbase)[gi] = f2bf(v + bias[gcol]);
        } else if (EPI == 1) {
          ((float*)Cbase)[gi] = v + bias[gcol] + Res[gi];
        } else {
          ((unsigned short*)Cbase)[gi] = f2bf(v);
        }
      }
    }
  }
}

// ---------------- G = Q^T Q per (b,n), chunked over s, atomic reduce ----------
__global__ __launch_bounds__(256) void compute_g(const unsigned short* __restrict__ fused,
                                                 float* __restrict__ G)
{
  __shared__ float Qs[64][128];
  const int z = blockIdx.x;            // b*32+n
  const int b = z >> 5, n = z & 31;
  const unsigned short* Q = fused + (long)b * S_ * H3_ + n * 384;
  const int t = threadIdx.x;
  const int t1 = t >> 4, t2 = t & 15;
  float acc[8][8];
#pragma unroll
  for (int a = 0; a < 8; ++a)
#pragma unroll
    for (int c = 0; c < 8; ++c) acc[a][c] = 0.f;

  const int sbeg = blockIdx.y * 512;
  for (int s0 = sbeg; s0 < sbeg + 512; s0 += 64) {
#pragma unroll
    for (int ii = 0; ii < 4; ++ii) {
      const int r = ii * 16 + t1;
      float f[8];
      unpack8(*(const uint4*)(Q + (long)(s0 + r) * H3_ + t2 * 8), f);
#pragma unroll
      for (int j = 0; j < 8; ++j) Qs[r][t2 * 8 + j] = f[j];
    }
    __syncthreads();
    for (int ss = 0; ss < 64; ++ss) {
      float qa[8], qb[8];
#pragma unroll
      for (int j = 0; j < 8; ++j) { qa[j] = Qs[ss][t1 * 8 + j]; qb[j] = Qs[ss][t2 * 8 + j]; }
#pragma unroll
      for (int a = 0; a < 8; ++a)
#pragma unroll
        for (int c = 0; c < 8; ++c) acc[a][c] += qa[a] * qb[c];
    }
    __syncthreads();
  }
  float* Gz = G + (long)z * 16384;
#pragma unroll
  for (int a = 0; a < 8; ++a)
#pragma unroll
    for (int c = 0; c < 8; ++c)
      atomicAdd(&Gz[(t1 * 8 + a) * 128 + t2 * 8 + c], acc[a][c]);
}

// ---------------- register-resident Gauss-Jordan inverse of SPD 128x128 ------
__global__ __launch_bounds__(1024) void invert_g(const float* __restrict__ G,
                                                 unsigned short* __restrict__ Ginv)
{
  __shared__ __align__(16) float prow[2][128];
  __shared__ __align__(16) float pcol[2][128];
  const int z = blockIdx.x;
  const int t = threadIdx.x;
  const int c  = t & 127;
  const int rg = t >> 7;                 // 0..7 -> rows rg*16 .. rg*16+15
  const float* Gz = G + (long)z * 16384;

  float a[16];
#pragma unroll
  for (int i = 0; i < 16; ++i) a[i] = Gz[(rg * 16 + i) * 128 + c];

  for (int p = 0; p < 128; ++p) {
    const int buf = p & 1;
    const int prg = p >> 4, pi = p & 15;
    if (rg == prg) {
      float v = a[0];
#pragma unroll
      for (int i = 1; i < 16; ++i) v = (pi == i) ? a[i] : v;
      prow[buf][c] = v;
    }
    if (c == p) {
#pragma unroll
      for (int q = 0; q < 4; ++q) {
        float4 w4 = make_float4(a[q * 4], a[q * 4 + 1], a[q * 4 + 2], a[q * 4 + 3]);
        *(float4*)&pcol[buf][rg * 16 + q * 4] = w4;
      }
    }
    __syncthreads();
    const float invp = 1.0f / prow[buf][p];
    const float rowv = (c == p) ? invp : prow[buf][c] * invp;
#pragma unroll
    for (int q = 0; q < 4; ++q) {
      const float4 pc4 = *(const float4*)&pcol[buf][rg * 16 + q * 4];
      const float pcv[4] = {pc4.x, pc4.y, pc4.z, pc4.w};
#pragma unroll
      for (int j = 0; j < 4; ++j) {
        const int i = q * 4 + j;
        const int r = rg * 16 + i;
        const float cur = (c == p) ? 0.f : a[i];
        a[i] = (r == p) ? rowv : cur - pcv[j] * rowv;
      }
    }
  }
  unsigned short* Oz = Ginv + (long)z * 16384;
#pragma unroll
  for (int i = 0; i < 16; ++i) Oz[(rg * 16 + i) * 128 + c] = f2bf(a[i]);
}

// ---------------- per-position 32x32 head attention ----------------
__global__ __launch_bounds__(256) void attn_pos(
    const unsigned short* __restrict__ fused, const unsigned short* __restrict__ Zb,
    const float* __restrict__ alibi, unsigned short* __restrict__ ctx)
{
  __shared__ __align__(16) unsigned short qkv[H3_];
  __shared__ __align__(16) unsigned short zsh[H_];
  __shared__ float wsh[NH_][NH_ + 1];
  __shared__ float pden[NH_];
  __shared__ float alib[NH_];

  const int s = blockIdx.x, b = blockIdx.y;
  const int t = threadIdx.x;
  const unsigned short* src = fused + ((long)b * S_ + s) * H3_;
  for (int i = t * 8; i < H3_; i += 2048) *(uint4*)&qkv[i] = *(const uint4*)&src[i];
  const unsigned short* zsrc = Zb + ((long)b * S_ + s) * H_;
  for (int i = t * 8; i < H_; i += 2048) *(uint4*)&zsh[i] = *(const uint4*)&zsrc[i];
  if (t < NH_) alib[t] = 0.08838834764831845f * alibi[((long)(b * NH_ + t)) * S_ + s];
  __syncthreads();

  const int i = t >> 3;
  const int j0 = (t & 7) * 4;
  const int rot = (i ^ (t & 7)) & 15;
  float aqk[4] = {0.f, 0.f, 0.f, 0.f};
  float aqz[4] = {0.f, 0.f, 0.f, 0.f};
  for (int dbi = 0; dbi < 16; ++dbi) {
    const int d0b = ((dbi + rot) & 15) * 8;
    float qf[8];
    unpack8(*(const uint4*)&qkv[i * 384 + d0b], qf);
#pragma unroll
    for (int jj = 0; jj < 4; ++jj) {
      const int j = j0 + jj;
      float kf[8], zf[8];
      unpack8(*(const uint4*)&qkv[j * 384 + 128 + d0b], kf);
      unpack8(*(const uint4*)&zsh[j * 128 + d0b], zf);
#pragma unroll
      for (int d = 0; d < 8; ++d) { aqk[jj] += qf[d] * kf[d]; aqz[jj] += qf[d] * zf[d]; }
    }
  }
#pragma unroll
  for (int jj = 0; jj < 4; ++jj)
    wsh[i][j0 + jj] = 0.0078125f * aqk[jj] + alib[j0 + jj] * aqz[jj];
  __syncthreads();

  if (t < NH_) {
    float m = -1e30f;
    for (int j = 0; j < NH_; ++j) m = fmaxf(m, wsh[t][j]);
    float ssum = 0.f;
    for (int j = 0; j < NH_; ++j) { float e = __expf(wsh[t][j] - m); wsh[t][j] = e; ssum += e; }
    pden[t] = 1.0f / (ssum + 1e-8f);
  }
  __syncthreads();

  const int d0 = (t & 7) * 16;
  float acc[16];
#pragma unroll
  for (int d = 0; d < 16; ++d) acc[d] = 0.f;
  for (int j = 0; j < NH_; ++j) {
    const float p = wsh[i][j];
    float vf[16];
    unpack8(*(const uint4*)&qkv[j * 384 + 256 + d0], vf);
    unpack8(*(const uint4*)&qkv[j * 384 + 256 + d0 + 8], vf + 8);
#pragma unroll
    for (int d = 0; d < 16; ++d) acc[d] += p * vf[d];
  }
  const float inv = pden[i];
  union { uint4 u[2]; unsigned short us[16]; } ov;
#pragma unroll
  for (int d = 0; d < 16; ++d) ov.us[d] = f2bf(acc[d] * inv);
  unsigned short* cp = ctx + ((long)b * S_ + s) * H_ + i * HD_ + d0;
  *(uint4*)&cp[0] = ov.u[0];
  *(uint4*)&cp[8] = ov.u[1];
}

// -----------------------------------------------------------------------------
extern "C" void kernel_launch(void* const* d_in, const int* in_sizes, int n_in,
                              void* d_out, int out_size, void* d_ws, size_t ws_size,
                              hipStream_t stream)
{
  (void)in_sizes; (void)n_in; (void)out_size; (void)ws_size;
  const float* hidden   = (const float*)d_in[0];
  const float* residual = (const float*)d_in[1];
  const float* alibi    = (const float*)d_in[2];
  const float* Wqkv     = (const float*)d_in[4];
  const float* bqkv     = (const float*)d_in[5];
  const float* Wd       = (const float*)d_in[6];
  const float* bd       = (const float*)d_in[7];
  float* out = (float*)d_out;

  char* ws = (char*)d_ws;
  size_t off = 0;
  auto carve = [&](size_t bytes) -> void* {
    void* p = ws + off;
    off += (bytes + 255) & ~(size_t)255;
    return p;
  };
  const long nHid = (long)B_ * S_ * H_;
  const long nWq  = (long)H3_ * H_;
  unsigned short* hid_bf   = (unsigned short*)carve((size_t)nHid * 2);
  unsigned short* wqkv_bf  = (unsigned short*)carve((size_t)nWq * 2);
  unsigned short* wd_bf    = (unsigned short*)carve((size_t)H_ * H_ * 2);
  unsigned short* fused_bf = (unsigned short*)carve((size_t)B_ * S_ * H3_ * 2);
  unsigned short* z_bf     = (unsigned short*)carve((size_t)nHid * 2);
  unsigned short* ctx_bf   = (unsigned short*)carve((size_t)nHid * 2);
  float*          Gbuf     = (float*)carve((size_t)64 * 16384 * 4);
  unsigned short* ginv_bf  = (unsigned short*)carve((size_t)64 * 16384 * 2);

  // 1) bf16 casts
  cvt_bf16<<<2048, 256, 0, stream>>>(hidden, hid_bf, nHid);
  cvt_bf16<<<2048, 256, 0, stream>>>(Wqkv, wqkv_bf, nWq);
  cvt_bf16<<<2048, 256, 0, stream>>>(Wd, wd_bf, (long)H_ * H_);

  // 2) fused = hidden @ Wqkv^T + b_qkv  (bf16 out) — 256² pipelined GEMM
  gemm256<0><<<dim3(H3_ / 256, (B_ * S_) / 256, 1), 512, 0, stream>>>(
      hid_bf, wqkv_bf, fused_bf, bqkv, nullptr, H_, H_, H3_, H_);

  // 3) G = Q^T Q per (b,n); then Ginv via register-resident Gauss-Jordan
  hipMemsetAsync(Gbuf, 0, (size_t)64 * 16384 * 4, stream);
  compute_g<<<dim3(64, 4), 256, 0, stream>>>(fused_bf, Gbuf);
  invert_g<<<64, 1024, 0, stream>>>(Gbuf, ginv_bf);

  // 4) Z[b,s,n,:] = Ginv_{b,n} q_{b,n}(s)   (small batched GEMM, 128² kernel)
  gemm_bt<2><<<dim3(1, S_ / 128, 64), 256, 0, stream>>>(
      fused_bf, ginv_bf, z_bf, nullptr, nullptr, H3_, HD_, H_, HD_,
      (long)S_ * H3_, 384, (long)32 * 16384, 16384, (long)S_ * H_, HD_);

  // 5) per-position 32x32 head attention -> ctx (bf16)
  attn_pos<<<dim3(S_, B_), 256, 0, stream>>>(fused_bf, z_bf, alibi, ctx_bf);

  // 6) out = ctx @ Wd^T + b_dense + residual  (f32 out) — 256² pipelined GEMM
  gemm256<1><<<dim3(H_ / 256, (B_ * S_) / 256, 1), 512, 0, stream>>>(
      ctx_bf, wd_bf, out, bd, residual, H_, H_, H_, H_);
}